// Round 10
// baseline (371.120 us; speedup 1.0000x reference)
//
#include <hip/hip_runtime.h>
#include <hip/hip_bf16.h>
#include <math.h>

#define D_MODEL 1024
#define N_HEADS 16
#define D_HEAD  64
#define D_FF    4096
#define BATCH   2
#define SEQ     2048
#define NTOK    (BATCH*SEQ)

typedef __hip_bfloat16 bf16;
typedef __attribute__((ext_vector_type(8))) short short8;
typedef __attribute__((ext_vector_type(4))) float floatx4;

// ---------------- LayerNorm ----------------
template<typename TIN>
__global__ void ln_kernel(const TIN* __restrict__ x,
                          const float* __restrict__ w,
                          const float* __restrict__ b,
                          bf16* __restrict__ out) {
    int row = blockIdx.x;
    int tid = threadIdx.x;
    const long base = (long)row * D_MODEL;
    float v[4];
    float s = 0.f, sq = 0.f;
#pragma unroll
    for (int i = 0; i < 4; ++i) {
        float xv = (float)x[base + tid + i*256];
        v[i] = xv; s += xv; sq += xv*xv;
    }
    __shared__ float r1[256], r2[256];
    r1[tid] = s; r2[tid] = sq; __syncthreads();
    for (int off = 128; off > 0; off >>= 1) {
        if (tid < off) { r1[tid] += r1[tid+off]; r2[tid] += r2[tid+off]; }
        __syncthreads();
    }
    float mean = r1[0] * (1.f/D_MODEL);
    float var  = r2[0] * (1.f/D_MODEL) - mean*mean;
    float rstd = rsqrtf(var + 1e-5f);
#pragma unroll
    for (int i = 0; i < 4; ++i) {
        int c = tid + i*256;
        out[base + c] = __float2bfloat16((v[i] - mean) * rstd * w[c] + b[c]);
    }
}

// ---------------- weight convert+transpose: fp32 [K][N] -> bf16 [N][K] ----------------
__global__ __launch_bounds__(256) void wcvt_kernel(const float* __restrict__ W,
                                                   bf16* __restrict__ Wt,
                                                   int K, int N) {
    __shared__ float t[32][33];
    int n0 = blockIdx.x * 32, k0 = blockIdx.y * 32;
    int lx = threadIdx.x & 31, ly = threadIdx.x >> 5;
#pragma unroll
    for (int i = 0; i < 4; ++i) {
        int k = ly + i * 8;
        t[k][lx] = W[(long)(k0 + k) * N + n0 + lx];
    }
    __syncthreads();
#pragma unroll
    for (int i = 0; i < 4; ++i) {
        int n = ly + i * 8;
        Wt[(long)(n0 + n) * K + k0 + lx] = __float2bfloat16(t[lx][n]);
    }
}

// merged Wo+W1 convert (both K=1024): gx<32 -> Wo cols, else W1 cols
__global__ __launch_bounds__(256) void wcvt_wo_w1(const float* __restrict__ Wo,
                                                  const float* __restrict__ W1,
                                                  bf16* __restrict__ wo_bf,
                                                  bf16* __restrict__ w1_bf) {
    __shared__ float t[32][33];
    int gx = blockIdx.x;
    const float* W; bf16* Wt; int N, n0;
    if (gx < 32) { W = Wo; Wt = wo_bf; N = D_MODEL; n0 = gx * 32; }
    else         { W = W1; Wt = w1_bf; N = D_FF;    n0 = (gx - 32) * 32; }
    int k0 = blockIdx.y * 32;
    int lx = threadIdx.x & 31, ly = threadIdx.x >> 5;
#pragma unroll
    for (int i = 0; i < 4; ++i) {
        int k = ly + i * 8;
        t[k][lx] = W[(long)(k0 + k) * N + n0 + lx];
    }
    __syncthreads();
#pragma unroll
    for (int i = 0; i < 4; ++i) {
        int n = ly + i * 8;
        Wt[(long)(n0 + n) * D_MODEL + k0 + lx] = __float2bfloat16(t[lx][n]);
    }
}

// per-head QKV weight convert: -> wqkv_bf[3072][1024] bf16 N-major (n = mat*1024+head*64+d)
__global__ __launch_bounds__(256) void wcvt_qkv(const float* __restrict__ Wq,
                                                const float* __restrict__ Wk,
                                                const float* __restrict__ Wv,
                                                bf16* __restrict__ outp) {
    __shared__ float t[32][33];
    int z = blockIdx.z, mat = z >> 4, head = z & 15;
    const float* W = (mat == 0 ? Wq : mat == 1 ? Wk : Wv) + (long)head * D_MODEL * D_HEAD;
    bf16* Wt = outp + (long)z * D_HEAD * D_MODEL;
    int n0 = blockIdx.x * 32, k0 = blockIdx.y * 32;
    int lx = threadIdx.x & 31, ly = threadIdx.x >> 5;
#pragma unroll
    for (int i = 0; i < 4; ++i) {
        int k = ly + i * 8;
        t[k][lx] = W[(long)(k0 + k) * D_HEAD + n0 + lx];
    }
    __syncthreads();
#pragma unroll
    for (int i = 0; i < 4; ++i) {
        int n = ly + i * 8;
        Wt[(long)(n0 + n) * D_MODEL + k0 + lx] = __float2bfloat16(t[lx][n]);
    }
}

// ---------------- XCD-chunked block swizzle (requires nwg % 8 == 0) ----------------
__device__ inline void swz2d(int& bx, int& by) {
    int gx = gridDim.x;
    int nwg = gx * gridDim.y;
    int bid = blockIdx.y * gx + blockIdx.x;
    int swz = (bid & 7) * (nwg >> 3) + (bid >> 3);
    bx = swz % gx;
    by = swz / gx;
}

// ---------------- async stage: ROWS x 32 bf16 tile (64B rows, unpadded) ----------------
template<int ROWS>
__device__ inline void stage_tile(const bf16* g, int gstride, short* lds) {
    int lane = threadIdx.x & 63, wave = threadIdx.x >> 6;
#pragma unroll
    for (int it = 0; it < ROWS / 64; ++it) {
        int c = wave + it * 4;
        const bf16* gp = g + (long)(c * 16 + (lane >> 2)) * gstride + (lane & 3) * 8;
        short* lp = lds + c * 512 + lane * 8;
        __builtin_amdgcn_global_load_lds(
            (const __attribute__((address_space(1))) void*)gp,
            (__attribute__((address_space(3))) void*)lp, 16, 0, 0);
    }
}

// ---------------- sync / asm helpers ----------------
#define G256_BAR  asm volatile("s_barrier" ::: "memory")
#define G256_VM12 asm volatile("s_waitcnt vmcnt(12)" ::: "memory")
#define G256_VM6  asm volatile("s_waitcnt vmcnt(6)" ::: "memory")
#define G256_VM4  asm volatile("s_waitcnt vmcnt(4)" ::: "memory")
#define G256_VM0  asm volatile("s_waitcnt vmcnt(0)" ::: "memory")
#define G256_LGKM0 do { asm volatile("s_waitcnt lgkmcnt(0)" ::: "memory"); \
                        __builtin_amdgcn_sched_barrier(0); } while (0)

__device__ inline short8 rd128(unsigned ad) {
    short8 r;
    asm volatile("ds_read_b128 %0, %1" : "=v"(r) : "v"(ad));
    return r;
}

// ---------------- 3-deep counted-vmcnt pipeline GEMM (4b / 7b) ---------------------
template<int BM, int BN, int BK, int BIAS, int ACT, int RES, int OUTBF16>
__global__ __launch_bounds__(256) void mfma_gemm_pipe3(
    const bf16* __restrict__ A, int lda,
    const bf16* __restrict__ Wt, int K,
    const float* __restrict__ bias, const float* __restrict__ resid,
    void* __restrict__ Cout, int ldc)
{
    constexpr int MI  = BM / 32;
    constexpr int NR  = BN / 32;
    constexpr int ASZ = BM * BK;
    constexpr int BSZ = BN * BK;
    __shared__ short As[3 * BM * BK];
    __shared__ short Bs[3 * BN * BK];
    int bx, by; swz2d(bx, by);
    int row0 = by * BM, col0 = bx * BN;
    int tid = threadIdx.x, wave = tid >> 6, lane = tid & 63;
    int quad = lane >> 4, l16 = lane & 15;
    int wm = (wave >> 1) * (BM / 2);
    int wn = (wave & 1) * (BN / 2);
    const int NT = K / BK;

    auto stage = [&](int t, int buf) {
        int k0 = t * BK;
#pragma unroll
        for (int kk = 0; kk < BK; kk += 32) {
            stage_tile<BM>(A  + (long)row0 * lda + k0 + kk, lda,
                           As + buf * ASZ + (kk / 32) * BM * 32);
            stage_tile<BN>(Wt + (long)col0 * K   + k0 + kk, K,
                           Bs + buf * BSZ + (kk / 32) * BN * 32);
        }
    };

    unsigned asbase = (unsigned)(unsigned long long)(void*)&As[0];
    unsigned bsbase = (unsigned)(unsigned long long)(void*)&Bs[0];
    unsigned aRow[MI], bRow[NR];
#pragma unroll
    for (int mi = 0; mi < MI; ++mi)
        aRow[mi] = (unsigned)(((wm + mi * 16 + l16) * 32 + quad * 8) * 2);
#pragma unroll
    for (int ni = 0; ni < NR; ++ni)
        bRow[ni] = (unsigned)(((wn + ni * 16 + l16) * 32 + quad * 8) * 2);

    floatx4 acc[MI][NR];
#pragma unroll
    for (int mi = 0; mi < MI; ++mi)
#pragma unroll
        for (int ni = 0; ni < NR; ++ni)
            acc[mi][ni] = (floatx4){0.f, 0.f, 0.f, 0.f};

    stage(0, 0);
    if (NT > 1) stage(1, 1);
    if (NT > 2) stage(2, 2);

    int buf = 0;
    for (int i = 0; i < NT; ++i) {
        if (i + 2 < NT)      { G256_VM12; }
        else if (i + 1 < NT) { G256_VM6;  }
        else                 { G256_VM0;  }
        G256_BAR;

        short8 af[BK / 32][MI], bfr[BK / 32][NR];
#pragma unroll
        for (int p = 0; p < BK / 32; ++p) {
            unsigned ab = asbase + (unsigned)((buf * ASZ + p * BM * 32) * 2);
            unsigned bb = bsbase + (unsigned)((buf * BSZ + p * BN * 32) * 2);
#pragma unroll
            for (int mi = 0; mi < MI; ++mi) af[p][mi] = rd128(ab + aRow[mi]);
#pragma unroll
            for (int ni = 0; ni < NR; ++ni) bfr[p][ni] = rd128(bb + bRow[ni]);
        }
        G256_LGKM0;
#pragma unroll
        for (int p = 0; p < BK / 32; ++p)
#pragma unroll
            for (int mi = 0; mi < MI; ++mi)
#pragma unroll
                for (int ni = 0; ni < NR; ++ni)
                    acc[mi][ni] = __builtin_amdgcn_mfma_f32_16x16x32_bf16(
                        af[p][mi], bfr[p][ni], acc[mi][ni], 0, 0, 0);

        G256_BAR;
        if (i + 3 < NT) stage(i + 3, buf);
        buf = (buf == 2) ? 0 : buf + 1;
    }

#pragma unroll
    for (int mi = 0; mi < MI; ++mi) {
#pragma unroll
        for (int ni = 0; ni < NR; ++ni) {
#pragma unroll
            for (int r = 0; r < 4; ++r) {
                int row = row0 + wm + mi * 16 + quad * 4 + r;
                int col = col0 + wn + ni * 16 + l16;
                float v = acc[mi][ni][r];
                if (BIAS) v += bias[col];
                if (ACT == 1) {
                    float x2 = v * v;
                    float arg = fminf(v * fmaf(0.1029392f, x2, 2.3021182f), 20.f);
                    float t = exp2f(arg);
                    v = v * t * __builtin_amdgcn_rcpf(t + 1.f);
                }
                long idx = (long)row * ldc + col;
                if (RES == 1) v += resid[idx];
                if (OUTBF16) ((bf16*)Cout)[idx] = __float2bfloat16(v);
                else         ((float*)Cout)[idx] = v;
            }
        }
    }
}

// ================= 8-phase 256x256 GEMM (QKV / FFN1) ===============================
struct QkvOut { bf16* o[3]; };

#define RG(buf,mat,kh) (((buf)*4 + (mat)*2 + (kh)) * 8192)

__device__ inline void stage2(const bf16* g0, const bf16* g1, int koff, short* lp) {
    __builtin_amdgcn_global_load_lds(
        (const __attribute__((address_space(1))) void*)(g0 + koff),
        (__attribute__((address_space(3))) void*)lp, 16, 0, 0);
    __builtin_amdgcn_global_load_lds(
        (const __attribute__((address_space(1))) void*)(g1 + koff),
        (__attribute__((address_space(3))) void*)(lp + 4096), 16, 0, 0);
}

template<int MH>
__device__ inline void rd_frags_asm(unsigned ldsbase, int ra, int rb,
                                    const unsigned (&aoff)[8], const unsigned (&boff)[4],
                                    short8 (&areg)[4], short8 (&breg)[4]) {
    if (MH == 0) {
#pragma unroll
        for (int ni = 0; ni < 4; ++ni) {
            unsigned ad = ldsbase + (unsigned)(rb * 2) + boff[ni];
            asm volatile("ds_read_b128 %0, %1" : "=v"(breg[ni]) : "v"(ad));
        }
    }
#pragma unroll
    for (int mi = 0; mi < 4; ++mi) {
        unsigned ad = ldsbase + (unsigned)(ra * 2) + aoff[MH * 4 + mi];
        asm volatile("ds_read_b128 %0, %1" : "=v"(areg[mi]) : "v"(ad));
    }
}

template<int MH>
__device__ inline void do_mfma16(const short8 (&areg)[4], const short8 (&breg)[4],
                                 floatx4 (&acc)[8][4]) {
    __builtin_amdgcn_s_setprio(1);
#pragma unroll
    for (int mi = 0; mi < 4; ++mi)
#pragma unroll
        for (int ni = 0; ni < 4; ++ni)
            acc[MH * 4 + mi][ni] = __builtin_amdgcn_mfma_f32_16x16x32_bf16(
                areg[mi], breg[ni], acc[MH * 4 + mi][ni], 0, 0, 0);
    __builtin_amdgcn_s_setprio(0);
}

// EPI: 0 = bias+GELU -> bf16 (FFN1)   1 = QKV scatter
template<int EPI>
__global__ __launch_bounds__(512, 1) void gemm256_kernel(
    const bf16* __restrict__ A, int lda,
    const bf16* __restrict__ Wt, int ldw, int K,
    const float* __restrict__ bias,
    bf16* __restrict__ Cout, int ldc, QkvOut qa)
{
    __shared__ short lds[65536];   // 128 KiB
    const int NT = K / 64;
    int bx, by; swz2d(bx, by);
    int row0 = by * 256, col0 = bx * 256;
    int tid = threadIdx.x;
    int lane = tid & 63, wave = tid >> 6;
    int quad = lane >> 4, l16 = lane & 15;
    int wr = wave >> 2, wc = wave & 3;

    int srow = tid >> 2, slot = tid & 3;
    int cA0 = slot ^ ((srow >> 1) & 3);
    int cA1 = slot ^ (((srow + 128) >> 1) & 3);
    const bf16* a0 = A  + (long)(row0 + srow) * lda + cA0 * 8;
    const bf16* a1 = A  + (long)(row0 + srow + 128) * lda + cA1 * 8;
    const bf16* b0 = Wt + (long)(col0 + srow) * ldw + cA0 * 8;
    const bf16* b1 = Wt + (long)(col0 + srow + 128) * ldw + cA1 * 8;
    short* lt = lds + tid * 8;

    unsigned ldsbase = (unsigned)(unsigned long long)(void*)&lds[0];
    unsigned aoff[8], boff[4];
#pragma unroll
    for (int mi = 0; mi < 8; ++mi) {
        int row = wr * 128 + mi * 16 + l16;
        int sl = quad ^ ((row >> 1) & 3);
        aoff[mi] = (unsigned)((row * 32 + sl * 8) * 2);
    }
#pragma unroll
    for (int ni = 0; ni < 4; ++ni) {
        int row = wc * 64 + ni * 16 + l16;
        int sl = quad ^ ((row >> 1) & 3);
        boff[ni] = (unsigned)((row * 32 + sl * 8) * 2);
    }

    floatx4 acc[8][4];
#pragma unroll
    for (int mi = 0; mi < 8; ++mi)
#pragma unroll
        for (int ni = 0; ni < 4; ++ni)
            acc[mi][ni] = (floatx4){0.f, 0.f, 0.f, 0.f};

    stage2(a0, a1, 0,  lt + RG(0,0,0));
    stage2(b0, b1, 0,  lt + RG(0,1,0));
    stage2(a0, a1, 32, lt + RG(0,0,1));
    stage2(b0, b1, 32, lt + RG(0,1,1));
    stage2(a0, a1, 64, lt + RG(1,0,0));
    stage2(b0, b1, 64, lt + RG(1,1,0));
    G256_VM4;
    G256_BAR;

    short8 areg[4], breg[4];

    for (int i = 0; i < NT / 2; ++i) {
        int T = 2 * i;
        bool s2 = (T + 2 < NT);
        bool s3 = (T + 3 < NT);
        int k1off = (T + 1) * 64;
        int k2off = (T + 2) * 64;
        int k3off = (T + 3) * 64;

        rd_frags_asm<0>(ldsbase, RG(0,0,0), RG(0,1,0), aoff, boff, areg, breg);
        stage2(a0, a1, k1off + 32, lt + RG(1,0,1));
        G256_BAR;
        G256_LGKM0;
        do_mfma16<0>(areg, breg, acc);
        G256_BAR;

        rd_frags_asm<1>(ldsbase, RG(0,0,0), RG(0,1,0), aoff, boff, areg, breg);
        stage2(b0, b1, k1off + 32, lt + RG(1,1,1));
        G256_BAR;
        G256_LGKM0;
        do_mfma16<1>(areg, breg, acc);
        G256_BAR;

        rd_frags_asm<0>(ldsbase, RG(0,0,1), RG(0,1,1), aoff, boff, areg, breg);
        if (s2) stage2(a0, a1, k2off, lt + RG(0,0,0));
        G256_BAR;
        G256_LGKM0;
        do_mfma16<0>(areg, breg, acc);
        G256_BAR;

        rd_frags_asm<1>(ldsbase, RG(0,0,1), RG(0,1,1), aoff, boff, areg, breg);
        if (s2) stage2(b0, b1, k2off, lt + RG(0,1,0));
        G256_BAR;
        G256_LGKM0;
        do_mfma16<1>(areg, breg, acc);
        if (s2) { G256_VM4; } else { G256_VM0; }
        G256_BAR;

        rd_frags_asm<0>(ldsbase, RG(1,0,0), RG(1,1,0), aoff, boff, areg, breg);
        if (s2) stage2(a0, a1, k2off + 32, lt + RG(0,0,1));
        G256_BAR;
        G256_LGKM0;
        do_mfma16<0>(areg, breg, acc);
        G256_BAR;

        rd_frags_asm<1>(ldsbase, RG(1,0,0), RG(1,1,0), aoff, boff, areg, breg);
        if (s2) stage2(b0, b1, k2off + 32, lt + RG(0,1,1));
        G256_BAR;
        G256_LGKM0;
        do_mfma16<1>(areg, breg, acc);
        G256_BAR;

        rd_frags_asm<0>(ldsbase, RG(1,0,1), RG(1,1,1), aoff, boff, areg, breg);
        if (s3) stage2(a0, a1, k3off, lt + RG(1,0,0));
        G256_BAR;
        G256_LGKM0;
        do_mfma16<0>(areg, breg, acc);
        G256_BAR;

        rd_frags_asm<1>(ldsbase, RG(1,0,1), RG(1,1,1), aoff, boff, areg, breg);
        if (s3) stage2(b0, b1, k3off, lt + RG(1,1,0));
        G256_BAR;
        G256_LGKM0;
        do_mfma16<1>(areg, breg, acc);
        if (s3) { G256_VM4; } else { G256_VM0; }
        G256_BAR;
    }

#pragma unroll
    for (int mi = 0; mi < 8; ++mi) {
#pragma unroll
        for (int ni = 0; ni < 4; ++ni) {
#pragma unroll
            for (int r = 0; r < 4; ++r) {
                int row = row0 + wr * 128 + mi * 16 + quad * 4 + r;
                int col = col0 + wc * 64 + ni * 16 + l16;
                float v = acc[mi][ni][r];
                if constexpr (EPI == 0) {
                    v += bias[col];
                    float x2 = v * v;
                    float arg = fminf(v * fmaf(0.1029392f, x2, 2.3021182f), 20.f);
                    float t = exp2f(arg);
                    v = v * t * __builtin_amdgcn_rcpf(t + 1.f);
                    Cout[(long)row * ldc + col] = __float2bfloat16(v);
                } else {
                    int mat = col >> 10, hd = (col >> 6) & 15, d = col & 63;
                    int b = row >> 11, s = row & 2047;
                    qa.o[mat][(((long)(b * 16 + hd) * SEQ + s) << 6) + d] =
                        __float2bfloat16(v);
                }
            }
        }
    }
}

// ---------------- MFMA flash attention v7: QBLK=256/block (64 q rows per wave) -----
// Staging amortization: each kt-visit's K/V stage (loads + transpose + LDS writes)
// now serves 256 q rows instead of 128 -> total kt-visits halve. Ps (32 rows/wave)
// is wave-private and reused across the two rb-halves (h=0: rows 0-31, h=1: 32-63),
// so LDS stays 36 KB. Split-K balance: chunk0 handles tile=byr, chunk1 tile=7-byr
// -> per-CU pair work sums to a constant 18 kt-visits.
__global__ __launch_bounds__(256) void fattn_mfma(const bf16* __restrict__ q,
                                                  const bf16* __restrict__ k,
                                                  const bf16* __restrict__ v,
                                                  bf16* __restrict__ po,
                                                  float* __restrict__ lz) {
    int byr = blockIdx.y;
    int chunk = blockIdx.z;
    int tile = chunk ? 7 - byr : byr;            // complementary pairing across chunks
    int bh = blockIdx.x;
    int tid = threadIdx.x;
    int wave = tid >> 6, lane = tid & 63;
    int quad = lane >> 4, l16 = lane & 15;
    const long base = (long)bh * SEQ * D_HEAD;
    const int r0g = tile * 256;

    bf16*  pob = po + (long)chunk * 32 * SEQ * 64;
    float* lzb = lz + (long)chunk * 32 * SEQ;

    __shared__ short Ks[64 * 72];
    __shared__ short Vt[64 * 72];
    __shared__ short Ps[4][32 * 72];

    short8 qf[4][2];
#pragma unroll
    for (int rb = 0; rb < 4; ++rb) {
        const short* qrow = (const short*)(q + base +
            (long)(r0g + wave * 64 + rb * 16 + l16) * D_HEAD);
        qf[rb][0] = *(const short8*)(qrow + quad * 8);
        qf[rb][1] = *(const short8*)(qrow + 32 + quad * 8);
#pragma unroll
        for (int c = 0; c < 2; ++c)
#pragma unroll
            for (int j = 0; j < 8; ++j) {
                float f = __uint_as_float(((unsigned)(unsigned short)qf[rb][c][j]) << 16)
                          * 0.18033688f;
                qf[rb][c][j] = __builtin_bit_cast(short, __float2bfloat16(f));
            }
    }

    short8 onesf;
    {
        short o1 = (l16 == 0) ? (short)0x3F80 : (short)0;
#pragma unroll
        for (int j = 0; j < 8; ++j) onesf[j] = o1;
    }

    floatx4 o[4][4];
#pragma unroll
    for (int rb = 0; rb < 4; ++rb)
#pragma unroll
        for (int nb = 0; nb < 4; ++nb) o[rb][nb] = (floatx4){0.f, 0.f, 0.f, 0.f};
    floatx4 l4[4];
#pragma unroll
    for (int rb = 0; rb < 4; ++rb) l4[rb] = (floatx4){0.f, 0.f, 0.f, 0.f};

    // chunk0: kt in [0, 2t+1]; chunk1: kt in [2t+2, 4t+3] (equal counts 2t+2)
    const int kt0 = chunk ? 2 * tile + 2 : 0;
    const int kt1 = chunk ? 4 * tile + 3 : 2 * tile + 1;

    // staged K/V registers (async-STAGE split, T14)
    uint4 kr0, kr1, va4, vb4;
    auto ldKV = [&](int kt) {
        const short* krow = (const short*)(k + base +
            (long)(kt * 64 + (tid >> 2)) * D_HEAD);
        int c = tid & 3;
        kr0 = *(const uint4*)(krow + c * 16);
        kr1 = *(const uint4*)(krow + c * 16 + 8);
        int tp = (tid & 31) * 2;
        int d0 = ((tid >> 5) & 7) * 8;
        const short* v0 = (const short*)(v + base + (long)(kt * 64 + tp) * D_HEAD + d0);
        va4 = *(const uint4*)v0;
        vb4 = *(const uint4*)(v0 + D_HEAD);
    };

    ldKV(kt0);

    for (int kt = kt0; kt <= kt1; ++kt) {
        __syncthreads();     // previous compute done; Ks/Vt free
        {
            int t = tid >> 2, c = tid & 3;
            *(uint4*)&Ks[t * 72 + c * 16]     = kr0;
            *(uint4*)&Ks[t * 72 + c * 16 + 8] = kr1;
        }
        {
            int tp = (tid & 31) * 2;
            int d0 = ((tid >> 5) & 7) * 8;
            short va[8], vb[8];
            *(uint4*)va = va4;
            *(uint4*)vb = vb4;
#pragma unroll
            for (int j = 0; j < 8; ++j) {
                unsigned pk = (unsigned)(unsigned short)va[j] |
                              ((unsigned)(unsigned short)vb[j] << 16);
                *(unsigned*)&Vt[(d0 + j) * 72 + tp] = pk;
            }
        }
        if (kt < kt1) ldKV(kt + 1);   // next tile's loads hide under compute
        __syncthreads();

        // skip: all keys beyond this wave's last query
        if (kt * 64 > r0g + wave * 64 + 63) continue;
        bool domask = (kt >= 4 * tile + wave);

        short* Pw = &Ps[wave][0];
#pragma unroll
        for (int h = 0; h < 2; ++h) {
            floatx4 s[2][4];
            __builtin_amdgcn_s_setprio(1);
#pragma unroll
            for (int nb = 0; nb < 4; ++nb) {
                short8 kf0 = *(const short8*)&Ks[(nb * 16 + l16) * 72 + quad * 8];
                short8 kf1 = *(const short8*)&Ks[(nb * 16 + l16) * 72 + 32 + quad * 8];
#pragma unroll
                for (int rr = 0; rr < 2; ++rr) {
                    floatx4 z4 = (floatx4){0.f, 0.f, 0.f, 0.f};
                    z4 = __builtin_amdgcn_mfma_f32_16x16x32_bf16(qf[2*h+rr][0], kf0, z4, 0, 0, 0);
                    z4 = __builtin_amdgcn_mfma_f32_16x16x32_bf16(qf[2*h+rr][1], kf1, z4, 0, 0, 0);
                    s[rr][nb] = z4;
                }
            }
            __builtin_amdgcn_s_setprio(0);

            if (domask) {
#pragma unroll
                for (int rr = 0; rr < 2; ++rr) {
                    int qg = r0g + wave * 64 + (2*h+rr) * 16 + quad * 4;
#pragma unroll
                    for (int nb = 0; nb < 4; ++nb) {
                        int kg = kt * 64 + nb * 16 + l16;
#pragma unroll
                        for (int r = 0; r < 4; ++r)
                            if (kg > qg + r) s[rr][nb][r] = -1e30f;
                    }
                }
            }

#pragma unroll
            for (int rr = 0; rr < 2; ++rr)
#pragma unroll
                for (int nb = 0; nb < 4; ++nb)
#pragma unroll
                    for (int r = 0; r < 4; ++r) {
                        float p = exp2f(s[rr][nb][r]);
                        Pw[(rr * 16 + quad * 4 + r) * 72 + nb * 16 + l16] =
                            __builtin_bit_cast(short, __float2bfloat16(p));
                    }

            short8 pf[2][2];
#pragma unroll
            for (int rr = 0; rr < 2; ++rr) {
                pf[rr][0] = *(const short8*)&Pw[(rr * 16 + l16) * 72 + quad * 8];
                pf[rr][1] = *(const short8*)&Pw[(rr * 16 + l16) * 72 + 32 + quad * 8];
            }
            __builtin_amdgcn_s_setprio(1);
#pragma unroll
            for (int nb = 0; nb < 4; ++nb) {
                short8 vf0 = *(const short8*)&Vt[(nb * 16 + l16) * 72 + quad * 8];
                short8 vf1 = *(const short8*)&Vt[(nb * 16 + l16) * 72 + 32 + quad * 8];
#pragma unroll
                for (int rr = 0; rr < 2; ++rr) {
                    o[2*h+rr][nb] = __builtin_amdgcn_mfma_f32_16x16x32_bf16(
                        pf[rr][0], vf0, o[2*h+rr][nb], 0, 0, 0);
                    o[2*h+rr][nb] = __builtin_amdgcn_mfma_f32_16x16x32_bf16(
                        pf[rr][1], vf1, o[2*h+rr][nb], 0, 0, 0);
                }
            }
#pragma unroll
            for (int rr = 0; rr < 2; ++rr) {
                l4[2*h+rr] = __builtin_amdgcn_mfma_f32_16x16x32_bf16(
                    pf[rr][0], onesf, l4[2*h+rr], 0, 0, 0);
                l4[2*h+rr] = __builtin_amdgcn_mfma_f32_16x16x32_bf16(
                    pf[rr][1], onesf, l4[2*h+rr], 0, 0, 0);
            }
            __builtin_amdgcn_s_setprio(0);
        }
    }

    // epilogue: unnormalized O partial (bf16) + l partial (fp32)
#pragma unroll
    for (int rb = 0; rb < 4; ++rb) {
#pragma unroll
        for (int nb = 0; nb < 4; ++nb)
#pragma unroll
            for (int r = 0; r < 4; ++r) {
                int row = r0g + wave * 64 + rb * 16 + quad * 4 + r;
                pob[((long)bh * SEQ + row) * 64 + nb * 16 + l16] =
                    __float2bfloat16(o[rb][nb][r]);
            }
        if (l16 == 0) {
#pragma unroll
            for (int r = 0; r < 4; ++r) {
                int row = r0g + wave * 64 + rb * 16 + quad * 4 + r;
                lzb[(long)bh * SEQ + row] = l4[rb][r];
            }
        }
    }
}

// combine: cc[row][h*64+d] = (po0+po1)/(l0+l1); one block per token row
__global__ __launch_bounds__(256) void attn_combine(const bf16* __restrict__ po,
                                                    const float* __restrict__ lz,
                                                    bf16* __restrict__ cc) {
    const long CH = 32L * SEQ * 64;
    int row = blockIdx.x;
    int b = row >> 11, s = row & 2047;
    int tid = threadIdx.x;
    int col = tid * 4;
    int h = col >> 6, d = col & 63;
    long pidx = ((long)(b * 16 + h) * SEQ + s) * 64 + d;
    uint2 u0 = *(const uint2*)((const unsigned short*)po + pidx);
    uint2 u1 = *(const uint2*)((const unsigned short*)po + CH + pidx);
    long li = (long)(b * 16 + h) * SEQ + s;
    float linv = 1.f / (lz[li] + lz[32L * SEQ + li]);
    unsigned ua[4] = {u0.x & 0xFFFFu, u0.x >> 16, u0.y & 0xFFFFu, u0.y >> 16};
    unsigned ub[4] = {u1.x & 0xFFFFu, u1.x >> 16, u1.y & 0xFFFFu, u1.y >> 16};
    unsigned short rr[4];
#pragma unroll
    for (int i = 0; i < 4; ++i) {
        float ov = __uint_as_float(ua[i] << 16) + __uint_as_float(ub[i] << 16);
        rr[i] = __builtin_bit_cast(unsigned short, __float2bfloat16(ov * linv));
    }
    uint2 w;
    w.x = (unsigned)rr[0] | ((unsigned)rr[1] << 16);
    w.y = (unsigned)rr[2] | ((unsigned)rr[3] << 16);
    *(uint2*)((unsigned short*)cc + (long)row * D_MODEL + col) = w;
}

extern "C" void kernel_launch(void* const* d_in, const int* in_sizes, int n_in,
                              void* d_out, int out_size, void* d_ws, size_t ws_size,
                              hipStream_t stream) {
    const float* x    = (const float*)d_in[0];
    const float* Wq   = (const float*)d_in[2];
    const float* Wk   = (const float*)d_in[3];
    const float* Wv   = (const float*)d_in[4];
    const float* Wo   = (const float*)d_in[5];
    const float* ln1w = (const float*)d_in[6];
    const float* ln1b = (const float*)d_in[7];
    const float* ln2w = (const float*)d_in[8];
    const float* ln2b = (const float*)d_in[9];
    const float* W1   = (const float*)d_in[10];
    const float* b1   = (const float*)d_in[11];
    const float* W2   = (const float*)d_in[12];
    const float* b2   = (const float*)d_in[13];
    float* out = (float*)d_out;

    // Workspace (<=56 MB), att_x lives in d_out:
    //   [0,8)    h1 -> cc -> h2
    //   [8,16)   qb -> wo_bf[8,10) + w1_bf[10,18) -> w2_bf[8,16)
    //   [16,24)  kb
    //   [24,32)  vb ; [24,56) ff (after combine)
    //   [32,38)  wqkv_bf (dead before fattn)
    //   [32,48)  po (2 x 8 MiB attn O partials) ; [48,48.5) lz (2 x 256 KiB)
    char* wsb = (char*)d_ws;
    const size_t MB = 1024*1024;
    bf16*  h1      = (bf16*)(wsb + 0*MB);
    bf16*  qb      = (bf16*)(wsb + 8*MB);
    bf16*  kb      = (bf16*)(wsb + 16*MB);
    bf16*  vb      = (bf16*)(wsb + 24*MB);
    bf16*  wqkv_bf = (bf16*)(wsb + 32*MB);
    bf16*  po      = (bf16*)(wsb + 32*MB);
    float* lz      = (float*)(wsb + 48*MB);
    bf16*  cc      = (bf16*)(wsb + 0*MB);
    bf16*  wo_bf   = (bf16*)(wsb + 8*MB);
    bf16*  w1_bf   = (bf16*)(wsb + 10*MB);
    bf16*  h2      = (bf16*)(wsb + 0*MB);
    bf16*  ff      = (bf16*)(wsb + 24*MB);
    bf16*  w2_bf   = (bf16*)(wsb + 8*MB);

    QkvOut qa; qa.o[0] = qb; qa.o[1] = kb; qa.o[2] = vb;
    QkvOut qdummy = {};

    // 1. h1 = LN1(x)
    ln_kernel<float><<<NTOK, 256, 0, stream>>>(x, ln1w, ln1b, h1);

    // 2a. convert QKV weights -> wqkv_bf[3072][1024] bf16 N-major
    wcvt_qkv<<<dim3(2, 32, 48), 256, 0, stream>>>(Wq, Wk, Wv, wqkv_bf);

    // 2b. fused QKV as one 8-phase 256x256 GEMM (M=4096, N=3072, K=1024)
    gemm256_kernel<1><<<dim3(12, 16), 512, 0, stream>>>(
        h1, D_MODEL, wqkv_bf, D_MODEL, D_MODEL, nullptr, nullptr, 0, qa);

    // 3a. split-K flash attention, 256 q rows/block  (x=bh, y=tile idx, z=chunk)
    fattn_mfma<<<dim3(BATCH*N_HEADS, SEQ/256, 2), 256, 0, stream>>>(qb, kb, vb, po, lz);

    // 3b. combine partials -> concat
    attn_combine<<<NTOK, 256, 0, stream>>>(po, lz, cc);

    // 4a. convert Wo + W1 in one launch (qb/kb dead)
    wcvt_wo_w1<<<dim3(160, 32), 256, 0, stream>>>(Wo, W1, wo_bf, w1_bf);

    // 4b. att_x = x + cc @ Wo -> d_out (fp32): 3-deep counted-vmcnt pipeline
    mfma_gemm_pipe3<64,128,64,0,0,1,0><<<dim3(8,64), 256, 0, stream>>>(
        cc, D_MODEL, wo_bf, D_MODEL, nullptr, x, out, D_MODEL);

    // 5. h2 = LN2(att_x)
    ln_kernel<float><<<NTOK, 256, 0, stream>>>(out, ln2w, ln2b, h2);

    // 6. ff = GELU(h2 @ W1 + b1): 8-phase 256x256 GEMM (M=4096, N=4096, K=1024)
    gemm256_kernel<0><<<dim3(16, 16), 512, 0, stream>>>(
        h2, D_MODEL, w1_bf, D_MODEL, D_MODEL, b1, ff, D_FF, qdummy);

    // 7a. convert W2 (w1_bf/wo_bf dead)
    wcvt_kernel<<<dim3(D_MODEL/32, D_FF/32), 256, 0, stream>>>(W2, w2_bf, D_FF, D_MODEL);

    // 7b. out = att_x + ff @ W2 + b2: 3-deep counted-vmcnt pipeline
    mfma_gemm_pipe3<64,128,64,1,0,1,0><<<dim3(8,64), 256, 0, stream>>>(
        ff, D_FF, w2_bf, D_FF, b2, out, out, D_MODEL);
}

// Round 11
// 361.372 us; speedup vs baseline: 1.0270x; 1.0270x over previous
//
#include <hip/hip_runtime.h>
#include <hip/hip_bf16.h>
#include <math.h>

#define D_MODEL 1024
#define N_HEADS 16
#define D_HEAD  64
#define D_FF    4096
#define BATCH   2
#define SEQ     2048
#define NTOK    (BATCH*SEQ)

typedef __hip_bfloat16 bf16;
typedef __attribute__((ext_vector_type(8))) short short8;
typedef __attribute__((ext_vector_type(4))) float floatx4;

// ---------------- LayerNorm (wave-shuffle reduction: 2 barriers, no LDS tree) ------
template<typename TIN>
__global__ void ln_kernel(const TIN* __restrict__ x,
                          const float* __restrict__ w,
                          const float* __restrict__ b,
                          bf16* __restrict__ out) {
    int row = blockIdx.x;
    int tid = threadIdx.x;
    int wave = tid >> 6, lane = tid & 63;
    const long base = (long)row * D_MODEL;
    float v[4];
    float s = 0.f, sq = 0.f;
#pragma unroll
    for (int i = 0; i < 4; ++i) {
        float xv = (float)x[base + tid + i*256];
        v[i] = xv; s += xv; sq += xv*xv;
    }
    // 64-lane butterfly reduce (6 steps), then one cross-wave LDS step
#pragma unroll
    for (int m = 32; m >= 1; m >>= 1) {
        s  += __shfl_xor(s,  m, 64);
        sq += __shfl_xor(sq, m, 64);
    }
    __shared__ float r1[4], r2[4];
    if (lane == 0) { r1[wave] = s; r2[wave] = sq; }
    __syncthreads();
    float S  = r1[0] + r1[1] + r1[2] + r1[3];
    float SQ = r2[0] + r2[1] + r2[2] + r2[3];
    float mean = S * (1.f/D_MODEL);
    float var  = SQ * (1.f/D_MODEL) - mean*mean;
    float rstd = rsqrtf(var + 1e-5f);
#pragma unroll
    for (int i = 0; i < 4; ++i) {
        int c = tid + i*256;
        out[base + c] = __float2bfloat16((v[i] - mean) * rstd * w[c] + b[c]);
    }
}

// ---------------- weight convert+transpose: fp32 [K][N] -> bf16 [N][K] ----------------
__global__ __launch_bounds__(256) void wcvt_kernel(const float* __restrict__ W,
                                                   bf16* __restrict__ Wt,
                                                   int K, int N) {
    __shared__ float t[32][33];
    int n0 = blockIdx.x * 32, k0 = blockIdx.y * 32;
    int lx = threadIdx.x & 31, ly = threadIdx.x >> 5;
#pragma unroll
    for (int i = 0; i < 4; ++i) {
        int k = ly + i * 8;
        t[k][lx] = W[(long)(k0 + k) * N + n0 + lx];
    }
    __syncthreads();
#pragma unroll
    for (int i = 0; i < 4; ++i) {
        int n = ly + i * 8;
        Wt[(long)(n0 + n) * K + k0 + lx] = __float2bfloat16(t[lx][n]);
    }
}

// merged Wo+W1 convert (both K=1024): gx<32 -> Wo cols, else W1 cols
__global__ __launch_bounds__(256) void wcvt_wo_w1(const float* __restrict__ Wo,
                                                  const float* __restrict__ W1,
                                                  bf16* __restrict__ wo_bf,
                                                  bf16* __restrict__ w1_bf) {
    __shared__ float t[32][33];
    int gx = blockIdx.x;
    const float* W; bf16* Wt; int N, n0;
    if (gx < 32) { W = Wo; Wt = wo_bf; N = D_MODEL; n0 = gx * 32; }
    else         { W = W1; Wt = w1_bf; N = D_FF;    n0 = (gx - 32) * 32; }
    int k0 = blockIdx.y * 32;
    int lx = threadIdx.x & 31, ly = threadIdx.x >> 5;
#pragma unroll
    for (int i = 0; i < 4; ++i) {
        int k = ly + i * 8;
        t[k][lx] = W[(long)(k0 + k) * N + n0 + lx];
    }
    __syncthreads();
#pragma unroll
    for (int i = 0; i < 4; ++i) {
        int n = ly + i * 8;
        Wt[(long)(n0 + n) * D_MODEL + k0 + lx] = __float2bfloat16(t[lx][n]);
    }
}

// per-head QKV weight convert: -> wqkv_bf[3072][1024] bf16 N-major (n = mat*1024+head*64+d)
__global__ __launch_bounds__(256) void wcvt_qkv(const float* __restrict__ Wq,
                                                const float* __restrict__ Wk,
                                                const float* __restrict__ Wv,
                                                bf16* __restrict__ outp) {
    __shared__ float t[32][33];
    int z = blockIdx.z, mat = z >> 4, head = z & 15;
    const float* W = (mat == 0 ? Wq : mat == 1 ? Wk : Wv) + (long)head * D_MODEL * D_HEAD;
    bf16* Wt = outp + (long)z * D_HEAD * D_MODEL;
    int n0 = blockIdx.x * 32, k0 = blockIdx.y * 32;
    int lx = threadIdx.x & 31, ly = threadIdx.x >> 5;
#pragma unroll
    for (int i = 0; i < 4; ++i) {
        int k = ly + i * 8;
        t[k][lx] = W[(long)(k0 + k) * D_HEAD + n0 + lx];
    }
    __syncthreads();
#pragma unroll
    for (int i = 0; i < 4; ++i) {
        int n = ly + i * 8;
        Wt[(long)(n0 + n) * D_MODEL + k0 + lx] = __float2bfloat16(t[lx][n]);
    }
}

// ---------------- XCD-chunked block swizzle (requires nwg % 8 == 0) ----------------
__device__ inline void swz2d(int& bx, int& by) {
    int gx = gridDim.x;
    int nwg = gx * gridDim.y;
    int bid = blockIdx.y * gx + blockIdx.x;
    int swz = (bid & 7) * (nwg >> 3) + (bid >> 3);
    bx = swz % gx;
    by = swz / gx;
}

// ---------------- async stage: ROWS x 32 bf16 tile (64B rows, unpadded) ----------------
template<int ROWS>
__device__ inline void stage_tile(const bf16* g, int gstride, short* lds) {
    int lane = threadIdx.x & 63, wave = threadIdx.x >> 6;
#pragma unroll
    for (int it = 0; it < ROWS / 64; ++it) {
        int c = wave + it * 4;
        const bf16* gp = g + (long)(c * 16 + (lane >> 2)) * gstride + (lane & 3) * 8;
        short* lp = lds + c * 512 + lane * 8;
        __builtin_amdgcn_global_load_lds(
            (const __attribute__((address_space(1))) void*)gp,
            (__attribute__((address_space(3))) void*)lp, 16, 0, 0);
    }
}

// ---------------- sync / asm helpers ----------------
#define G256_BAR  asm volatile("s_barrier" ::: "memory")
#define G256_VM12 asm volatile("s_waitcnt vmcnt(12)" ::: "memory")
#define G256_VM6  asm volatile("s_waitcnt vmcnt(6)" ::: "memory")
#define G256_VM4  asm volatile("s_waitcnt vmcnt(4)" ::: "memory")
#define G256_VM0  asm volatile("s_waitcnt vmcnt(0)" ::: "memory")
#define G256_LGKM0 do { asm volatile("s_waitcnt lgkmcnt(0)" ::: "memory"); \
                        __builtin_amdgcn_sched_barrier(0); } while (0)

__device__ inline short8 rd128(unsigned ad) {
    short8 r;
    asm volatile("ds_read_b128 %0, %1" : "=v"(r) : "v"(ad));
    return r;
}

// ---------------- 3-deep counted-vmcnt pipeline GEMM (4b / 7b) ---------------------
template<int BM, int BN, int BK, int BIAS, int ACT, int RES, int OUTBF16>
__global__ __launch_bounds__(256) void mfma_gemm_pipe3(
    const bf16* __restrict__ A, int lda,
    const bf16* __restrict__ Wt, int K,
    const float* __restrict__ bias, const float* __restrict__ resid,
    void* __restrict__ Cout, int ldc)
{
    constexpr int MI  = BM / 32;
    constexpr int NR  = BN / 32;
    constexpr int ASZ = BM * BK;
    constexpr int BSZ = BN * BK;
    __shared__ short As[3 * BM * BK];
    __shared__ short Bs[3 * BN * BK];
    int bx, by; swz2d(bx, by);
    int row0 = by * BM, col0 = bx * BN;
    int tid = threadIdx.x, wave = tid >> 6, lane = tid & 63;
    int quad = lane >> 4, l16 = lane & 15;
    int wm = (wave >> 1) * (BM / 2);
    int wn = (wave & 1) * (BN / 2);
    const int NT = K / BK;

    auto stage = [&](int t, int buf) {
        int k0 = t * BK;
#pragma unroll
        for (int kk = 0; kk < BK; kk += 32) {
            stage_tile<BM>(A  + (long)row0 * lda + k0 + kk, lda,
                           As + buf * ASZ + (kk / 32) * BM * 32);
            stage_tile<BN>(Wt + (long)col0 * K   + k0 + kk, K,
                           Bs + buf * BSZ + (kk / 32) * BN * 32);
        }
    };

    unsigned asbase = (unsigned)(unsigned long long)(void*)&As[0];
    unsigned bsbase = (unsigned)(unsigned long long)(void*)&Bs[0];
    unsigned aRow[MI], bRow[NR];
#pragma unroll
    for (int mi = 0; mi < MI; ++mi)
        aRow[mi] = (unsigned)(((wm + mi * 16 + l16) * 32 + quad * 8) * 2);
#pragma unroll
    for (int ni = 0; ni < NR; ++ni)
        bRow[ni] = (unsigned)(((wn + ni * 16 + l16) * 32 + quad * 8) * 2);

    floatx4 acc[MI][NR];
#pragma unroll
    for (int mi = 0; mi < MI; ++mi)
#pragma unroll
        for (int ni = 0; ni < NR; ++ni)
            acc[mi][ni] = (floatx4){0.f, 0.f, 0.f, 0.f};

    stage(0, 0);
    if (NT > 1) stage(1, 1);
    if (NT > 2) stage(2, 2);

    int buf = 0;
    for (int i = 0; i < NT; ++i) {
        if (i + 2 < NT)      { G256_VM12; }
        else if (i + 1 < NT) { G256_VM6;  }
        else                 { G256_VM0;  }
        G256_BAR;

        short8 af[BK / 32][MI], bfr[BK / 32][NR];
#pragma unroll
        for (int p = 0; p < BK / 32; ++p) {
            unsigned ab = asbase + (unsigned)((buf * ASZ + p * BM * 32) * 2);
            unsigned bb = bsbase + (unsigned)((buf * BSZ + p * BN * 32) * 2);
#pragma unroll
            for (int mi = 0; mi < MI; ++mi) af[p][mi] = rd128(ab + aRow[mi]);
#pragma unroll
            for (int ni = 0; ni < NR; ++ni) bfr[p][ni] = rd128(bb + bRow[ni]);
        }
        G256_LGKM0;
#pragma unroll
        for (int p = 0; p < BK / 32; ++p)
#pragma unroll
            for (int mi = 0; mi < MI; ++mi)
#pragma unroll
                for (int ni = 0; ni < NR; ++ni)
                    acc[mi][ni] = __builtin_amdgcn_mfma_f32_16x16x32_bf16(
                        af[p][mi], bfr[p][ni], acc[mi][ni], 0, 0, 0);

        G256_BAR;
        if (i + 3 < NT) stage(i + 3, buf);
        buf = (buf == 2) ? 0 : buf + 1;
    }

#pragma unroll
    for (int mi = 0; mi < MI; ++mi) {
#pragma unroll
        for (int ni = 0; ni < NR; ++ni) {
#pragma unroll
            for (int r = 0; r < 4; ++r) {
                int row = row0 + wm + mi * 16 + quad * 4 + r;
                int col = col0 + wn + ni * 16 + l16;
                float v = acc[mi][ni][r];
                if (BIAS) v += bias[col];
                if (ACT == 1) {
                    float x2 = v * v;
                    float arg = fminf(v * fmaf(0.1029392f, x2, 2.3021182f), 20.f);
                    float t = exp2f(arg);
                    v = v * t * __builtin_amdgcn_rcpf(t + 1.f);
                }
                long idx = (long)row * ldc + col;
                if (RES == 1) v += resid[idx];
                if (OUTBF16) ((bf16*)Cout)[idx] = __float2bfloat16(v);
                else         ((float*)Cout)[idx] = v;
            }
        }
    }
}

// ================= 8-phase 256x256 GEMM (QKV / FFN1) ===============================
struct QkvOut { bf16* o[3]; };

#define RG(buf,mat,kh) (((buf)*4 + (mat)*2 + (kh)) * 8192)

__device__ inline void stage2(const bf16* g0, const bf16* g1, int koff, short* lp) {
    __builtin_amdgcn_global_load_lds(
        (const __attribute__((address_space(1))) void*)(g0 + koff),
        (__attribute__((address_space(3))) void*)lp, 16, 0, 0);
    __builtin_amdgcn_global_load_lds(
        (const __attribute__((address_space(1))) void*)(g1 + koff),
        (__attribute__((address_space(3))) void*)(lp + 4096), 16, 0, 0);
}

template<int MH>
__device__ inline void rd_frags_asm(unsigned ldsbase, int ra, int rb,
                                    const unsigned (&aoff)[8], const unsigned (&boff)[4],
                                    short8 (&areg)[4], short8 (&breg)[4]) {
    if (MH == 0) {
#pragma unroll
        for (int ni = 0; ni < 4; ++ni) {
            unsigned ad = ldsbase + (unsigned)(rb * 2) + boff[ni];
            asm volatile("ds_read_b128 %0, %1" : "=v"(breg[ni]) : "v"(ad));
        }
    }
#pragma unroll
    for (int mi = 0; mi < 4; ++mi) {
        unsigned ad = ldsbase + (unsigned)(ra * 2) + aoff[MH * 4 + mi];
        asm volatile("ds_read_b128 %0, %1" : "=v"(areg[mi]) : "v"(ad));
    }
}

template<int MH>
__device__ inline void do_mfma16(const short8 (&areg)[4], const short8 (&breg)[4],
                                 floatx4 (&acc)[8][4]) {
    __builtin_amdgcn_s_setprio(1);
#pragma unroll
    for (int mi = 0; mi < 4; ++mi)
#pragma unroll
        for (int ni = 0; ni < 4; ++ni)
            acc[MH * 4 + mi][ni] = __builtin_amdgcn_mfma_f32_16x16x32_bf16(
                areg[mi], breg[ni], acc[MH * 4 + mi][ni], 0, 0, 0);
    __builtin_amdgcn_s_setprio(0);
}

// EPI: 0 = bias+GELU -> bf16 (FFN1)   1 = QKV scatter
template<int EPI>
__global__ __launch_bounds__(512, 1) void gemm256_kernel(
    const bf16* __restrict__ A, int lda,
    const bf16* __restrict__ Wt, int ldw, int K,
    const float* __restrict__ bias,
    bf16* __restrict__ Cout, int ldc, QkvOut qa)
{
    __shared__ short lds[65536];   // 128 KiB
    const int NT = K / 64;
    int bx, by; swz2d(bx, by);
    int row0 = by * 256, col0 = bx * 256;
    int tid = threadIdx.x;
    int lane = tid & 63, wave = tid >> 6;
    int quad = lane >> 4, l16 = lane & 15;
    int wr = wave >> 2, wc = wave & 3;

    int srow = tid >> 2, slot = tid & 3;
    int cA0 = slot ^ ((srow >> 1) & 3);
    int cA1 = slot ^ (((srow + 128) >> 1) & 3);
    const bf16* a0 = A  + (long)(row0 + srow) * lda + cA0 * 8;
    const bf16* a1 = A  + (long)(row0 + srow + 128) * lda + cA1 * 8;
    const bf16* b0 = Wt + (long)(col0 + srow) * ldw + cA0 * 8;
    const bf16* b1 = Wt + (long)(col0 + srow + 128) * ldw + cA1 * 8;
    short* lt = lds + tid * 8;

    unsigned ldsbase = (unsigned)(unsigned long long)(void*)&lds[0];
    unsigned aoff[8], boff[4];
#pragma unroll
    for (int mi = 0; mi < 8; ++mi) {
        int row = wr * 128 + mi * 16 + l16;
        int sl = quad ^ ((row >> 1) & 3);
        aoff[mi] = (unsigned)((row * 32 + sl * 8) * 2);
    }
#pragma unroll
    for (int ni = 0; ni < 4; ++ni) {
        int row = wc * 64 + ni * 16 + l16;
        int sl = quad ^ ((row >> 1) & 3);
        boff[ni] = (unsigned)((row * 32 + sl * 8) * 2);
    }

    floatx4 acc[8][4];
#pragma unroll
    for (int mi = 0; mi < 8; ++mi)
#pragma unroll
        for (int ni = 0; ni < 4; ++ni)
            acc[mi][ni] = (floatx4){0.f, 0.f, 0.f, 0.f};

    stage2(a0, a1, 0,  lt + RG(0,0,0));
    stage2(b0, b1, 0,  lt + RG(0,1,0));
    stage2(a0, a1, 32, lt + RG(0,0,1));
    stage2(b0, b1, 32, lt + RG(0,1,1));
    stage2(a0, a1, 64, lt + RG(1,0,0));
    stage2(b0, b1, 64, lt + RG(1,1,0));
    G256_VM4;
    G256_BAR;

    short8 areg[4], breg[4];

    for (int i = 0; i < NT / 2; ++i) {
        int T = 2 * i;
        bool s2 = (T + 2 < NT);
        bool s3 = (T + 3 < NT);
        int k1off = (T + 1) * 64;
        int k2off = (T + 2) * 64;
        int k3off = (T + 3) * 64;

        rd_frags_asm<0>(ldsbase, RG(0,0,0), RG(0,1,0), aoff, boff, areg, breg);
        stage2(a0, a1, k1off + 32, lt + RG(1,0,1));
        G256_BAR;
        G256_LGKM0;
        do_mfma16<0>(areg, breg, acc);
        G256_BAR;

        rd_frags_asm<1>(ldsbase, RG(0,0,0), RG(0,1,0), aoff, boff, areg, breg);
        stage2(b0, b1, k1off + 32, lt + RG(1,1,1));
        G256_BAR;
        G256_LGKM0;
        do_mfma16<1>(areg, breg, acc);
        G256_BAR;

        rd_frags_asm<0>(ldsbase, RG(0,0,1), RG(0,1,1), aoff, boff, areg, breg);
        if (s2) stage2(a0, a1, k2off, lt + RG(0,0,0));
        G256_BAR;
        G256_LGKM0;
        do_mfma16<0>(areg, breg, acc);
        G256_BAR;

        rd_frags_asm<1>(ldsbase, RG(0,0,1), RG(0,1,1), aoff, boff, areg, breg);
        if (s2) stage2(b0, b1, k2off, lt + RG(0,1,0));
        G256_BAR;
        G256_LGKM0;
        do_mfma16<1>(areg, breg, acc);
        if (s2) { G256_VM4; } else { G256_VM0; }
        G256_BAR;

        rd_frags_asm<0>(ldsbase, RG(1,0,0), RG(1,1,0), aoff, boff, areg, breg);
        if (s2) stage2(a0, a1, k2off + 32, lt + RG(0,0,1));
        G256_BAR;
        G256_LGKM0;
        do_mfma16<0>(areg, breg, acc);
        G256_BAR;

        rd_frags_asm<1>(ldsbase, RG(1,0,0), RG(1,1,0), aoff, boff, areg, breg);
        if (s2) stage2(b0, b1, k2off + 32, lt + RG(0,1,1));
        G256_BAR;
        G256_LGKM0;
        do_mfma16<1>(areg, breg, acc);
        G256_BAR;

        rd_frags_asm<0>(ldsbase, RG(1,0,1), RG(1,1,1), aoff, boff, areg, breg);
        if (s3) stage2(a0, a1, k3off, lt + RG(1,0,0));
        G256_BAR;
        G256_LGKM0;
        do_mfma16<0>(areg, breg, acc);
        G256_BAR;

        rd_frags_asm<1>(ldsbase, RG(1,0,1), RG(1,1,1), aoff, boff, areg, breg);
        if (s3) stage2(b0, b1, k3off, lt + RG(1,1,0));
        G256_BAR;
        G256_LGKM0;
        do_mfma16<1>(areg, breg, acc);
        if (s3) { G256_VM4; } else { G256_VM0; }
        G256_BAR;
    }

#pragma unroll
    for (int mi = 0; mi < 8; ++mi) {
#pragma unroll
        for (int ni = 0; ni < 4; ++ni) {
#pragma unroll
            for (int r = 0; r < 4; ++r) {
                int row = row0 + wr * 128 + mi * 16 + quad * 4 + r;
                int col = col0 + wc * 64 + ni * 16 + l16;
                float v = acc[mi][ni][r];
                if constexpr (EPI == 0) {
                    v += bias[col];
                    float x2 = v * v;
                    float arg = fminf(v * fmaf(0.1029392f, x2, 2.3021182f), 20.f);
                    float t = exp2f(arg);
                    v = v * t * __builtin_amdgcn_rcpf(t + 1.f);
                    Cout[(long)row * ldc + col] = __float2bfloat16(v);
                } else {
                    int mat = col >> 10, hd = (col >> 6) & 15, d = col & 63;
                    int b = row >> 11, s = row & 2047;
                    qa.o[mat][(((long)(b * 16 + hd) * SEQ + s) << 6) + d] =
                        __float2bfloat16(v);
                }
            }
        }
    }
}

// ---------------- MFMA flash attention v6 (round-9 best): split-K + T14 + T5 ------
__global__ __launch_bounds__(256) void fattn_mfma(const bf16* __restrict__ q,
                                                  const bf16* __restrict__ k,
                                                  const bf16* __restrict__ v,
                                                  bf16* __restrict__ po,
                                                  float* __restrict__ lz) {
    int byr = blockIdx.y;
    int tile = (byr < 8) ? byr : 23 - byr;       // 0..15, balanced pairing
    int chunk = blockIdx.z;
    int bh = blockIdx.x;
    int tid = threadIdx.x;
    int wave = tid >> 6, lane = tid & 63;
    int quad = lane >> 4, l16 = lane & 15;
    const long base = (long)bh * SEQ * D_HEAD;
    const int r0g = tile * 128;

    bf16*  pob = po + (long)chunk * 32 * SEQ * 64;
    float* lzb = lz + (long)chunk * 32 * SEQ;

    __shared__ short Ks[64 * 72];
    __shared__ short Vt[64 * 72];
    __shared__ short Ps[4][32 * 72];

    short8 qf[2][2];
#pragma unroll
    for (int rb = 0; rb < 2; ++rb) {
        const short* qrow = (const short*)(q + base +
            (long)(r0g + wave * 32 + rb * 16 + l16) * D_HEAD);
        qf[rb][0] = *(const short8*)(qrow + quad * 8);
        qf[rb][1] = *(const short8*)(qrow + 32 + quad * 8);
#pragma unroll
        for (int c = 0; c < 2; ++c)
#pragma unroll
            for (int j = 0; j < 8; ++j) {
                float f = __uint_as_float(((unsigned)(unsigned short)qf[rb][c][j]) << 16)
                          * 0.18033688f;
                qf[rb][c][j] = __builtin_bit_cast(short, __float2bfloat16(f));
            }
    }

    short8 onesf;
    {
        short o1 = (l16 == 0) ? (short)0x3F80 : (short)0;
#pragma unroll
        for (int j = 0; j < 8; ++j) onesf[j] = o1;
    }

    floatx4 o[2][4];
#pragma unroll
    for (int rb = 0; rb < 2; ++rb)
#pragma unroll
        for (int nb = 0; nb < 4; ++nb) o[rb][nb] = (floatx4){0.f, 0.f, 0.f, 0.f};
    floatx4 l4[2] = {(floatx4){0.f,0.f,0.f,0.f}, (floatx4){0.f,0.f,0.f,0.f}};

    const int kt0 = chunk ? tile + 1 : 0;
    const int kt1 = chunk ? 2 * tile + 1 : tile;

    // staged K/V registers (async-STAGE split, T14)
    uint4 kr0, kr1, va4, vb4;
    auto ldKV = [&](int kt) {
        const short* krow = (const short*)(k + base +
            (long)(kt * 64 + (tid >> 2)) * D_HEAD);
        int c = tid & 3;
        kr0 = *(const uint4*)(krow + c * 16);
        kr1 = *(const uint4*)(krow + c * 16 + 8);
        int tp = (tid & 31) * 2;
        int d0 = ((tid >> 5) & 7) * 8;
        const short* v0 = (const short*)(v + base + (long)(kt * 64 + tp) * D_HEAD + d0);
        va4 = *(const uint4*)v0;
        vb4 = *(const uint4*)(v0 + D_HEAD);
    };

    ldKV(kt0);   // issue first tile's loads before the loop

    for (int kt = kt0; kt <= kt1; ++kt) {
        __syncthreads();     // previous compute done; Ks/Vt free
        {
            int t = tid >> 2, c = tid & 3;
            *(uint4*)&Ks[t * 72 + c * 16]     = kr0;
            *(uint4*)&Ks[t * 72 + c * 16 + 8] = kr1;
        }
        {
            int tp = (tid & 31) * 2;
            int d0 = ((tid >> 5) & 7) * 8;
            short va[8], vb[8];
            *(uint4*)va = va4;
            *(uint4*)vb = vb4;
#pragma unroll
            for (int j = 0; j < 8; ++j) {
                unsigned pk = (unsigned)(unsigned short)va[j] |
                              ((unsigned)(unsigned short)vb[j] << 16);
                *(unsigned*)&Vt[(d0 + j) * 72 + tp] = pk;
            }
        }
        if (kt < kt1) ldKV(kt + 1);   // next tile's loads hide under compute
        __syncthreads();

        if (kt * 64 > r0g + wave * 32 + 31) continue;

        floatx4 s[2][4];
        __builtin_amdgcn_s_setprio(1);
#pragma unroll
        for (int nb = 0; nb < 4; ++nb) {
            short8 kf0 = *(const short8*)&Ks[(nb * 16 + l16) * 72 + quad * 8];
            short8 kf1 = *(const short8*)&Ks[(nb * 16 + l16) * 72 + 32 + quad * 8];
#pragma unroll
            for (int rb = 0; rb < 2; ++rb) {
                floatx4 z4 = (floatx4){0.f, 0.f, 0.f, 0.f};
                z4 = __builtin_amdgcn_mfma_f32_16x16x32_bf16(qf[rb][0], kf0, z4, 0, 0, 0);
                z4 = __builtin_amdgcn_mfma_f32_16x16x32_bf16(qf[rb][1], kf1, z4, 0, 0, 0);
                s[rb][nb] = z4;
            }
        }
        __builtin_amdgcn_s_setprio(0);

        if (kt >= 2 * tile) {
#pragma unroll
            for (int rb = 0; rb < 2; ++rb) {
                int qg = r0g + wave * 32 + rb * 16 + quad * 4;
#pragma unroll
                for (int nb = 0; nb < 4; ++nb) {
                    int kg = kt * 64 + nb * 16 + l16;
#pragma unroll
                    for (int r = 0; r < 4; ++r)
                        if (kg > qg + r) s[rb][nb][r] = -1e30f;
                }
            }
        }

        short* Pw = &Ps[wave][0];
#pragma unroll
        for (int rb = 0; rb < 2; ++rb)
#pragma unroll
            for (int nb = 0; nb < 4; ++nb)
#pragma unroll
                for (int r = 0; r < 4; ++r) {
                    float p = exp2f(s[rb][nb][r]);
                    Pw[(rb * 16 + quad * 4 + r) * 72 + nb * 16 + l16] =
                        __builtin_bit_cast(short, __float2bfloat16(p));
                }

        short8 pf[2][2];
#pragma unroll
        for (int rb = 0; rb < 2; ++rb) {
            pf[rb][0] = *(const short8*)&Pw[(rb * 16 + l16) * 72 + quad * 8];
            pf[rb][1] = *(const short8*)&Pw[(rb * 16 + l16) * 72 + 32 + quad * 8];
        }
        __builtin_amdgcn_s_setprio(1);
#pragma unroll
        for (int nb = 0; nb < 4; ++nb) {
            short8 vf0 = *(const short8*)&Vt[(nb * 16 + l16) * 72 + quad * 8];
            short8 vf1 = *(const short8*)&Vt[(nb * 16 + l16) * 72 + 32 + quad * 8];
#pragma unroll
            for (int rb = 0; rb < 2; ++rb) {
                o[rb][nb] = __builtin_amdgcn_mfma_f32_16x16x32_bf16(pf[rb][0], vf0, o[rb][nb], 0, 0, 0);
                o[rb][nb] = __builtin_amdgcn_mfma_f32_16x16x32_bf16(pf[rb][1], vf1, o[rb][nb], 0, 0, 0);
            }
        }
#pragma unroll
        for (int rb = 0; rb < 2; ++rb) {
            l4[rb] = __builtin_amdgcn_mfma_f32_16x16x32_bf16(pf[rb][0], onesf, l4[rb], 0, 0, 0);
            l4[rb] = __builtin_amdgcn_mfma_f32_16x16x32_bf16(pf[rb][1], onesf, l4[rb], 0, 0, 0);
        }
        __builtin_amdgcn_s_setprio(0);
    }

    // epilogue: unnormalized O partial (bf16) + l partial (fp32)
#pragma unroll
    for (int rb = 0; rb < 2; ++rb) {
#pragma unroll
        for (int nb = 0; nb < 4; ++nb)
#pragma unroll
            for (int r = 0; r < 4; ++r) {
                int row = r0g + wave * 32 + rb * 16 + quad * 4 + r;
                pob[((long)bh * SEQ + row) * 64 + nb * 16 + l16] =
                    __float2bfloat16(o[rb][nb][r]);
            }
        if (l16 == 0) {
#pragma unroll
            for (int r = 0; r < 4; ++r) {
                int row = r0g + wave * 32 + rb * 16 + quad * 4 + r;
                lzb[(long)bh * SEQ + row] = l4[rb][r];
            }
        }
    }
}

// combine: cc[row][h*64+d] = (po0+po1)/(l0+l1); one block per token row
__global__ __launch_bounds__(256) void attn_combine(const bf16* __restrict__ po,
                                                    const float* __restrict__ lz,
                                                    bf16* __restrict__ cc) {
    const long CH = 32L * SEQ * 64;
    int row = blockIdx.x;
    int b = row >> 11, s = row & 2047;
    int tid = threadIdx.x;
    int col = tid * 4;
    int h = col >> 6, d = col & 63;
    long pidx = ((long)(b * 16 + h) * SEQ + s) * 64 + d;
    uint2 u0 = *(const uint2*)((const unsigned short*)po + pidx);
    uint2 u1 = *(const uint2*)((const unsigned short*)po + CH + pidx);
    long li = (long)(b * 16 + h) * SEQ + s;
    float linv = 1.f / (lz[li] + lz[32L * SEQ + li]);
    unsigned ua[4] = {u0.x & 0xFFFFu, u0.x >> 16, u0.y & 0xFFFFu, u0.y >> 16};
    unsigned ub[4] = {u1.x & 0xFFFFu, u1.x >> 16, u1.y & 0xFFFFu, u1.y >> 16};
    unsigned short rr[4];
#pragma unroll
    for (int i = 0; i < 4; ++i) {
        float ov = __uint_as_float(ua[i] << 16) + __uint_as_float(ub[i] << 16);
        rr[i] = __builtin_bit_cast(unsigned short, __float2bfloat16(ov * linv));
    }
    uint2 w;
    w.x = (unsigned)rr[0] | ((unsigned)rr[1] << 16);
    w.y = (unsigned)rr[2] | ((unsigned)rr[3] << 16);
    *(uint2*)((unsigned short*)cc + (long)row * D_MODEL + col) = w;
}

extern "C" void kernel_launch(void* const* d_in, const int* in_sizes, int n_in,
                              void* d_out, int out_size, void* d_ws, size_t ws_size,
                              hipStream_t stream) {
    const float* x    = (const float*)d_in[0];
    const float* Wq   = (const float*)d_in[2];
    const float* Wk   = (const float*)d_in[3];
    const float* Wv   = (const float*)d_in[4];
    const float* Wo   = (const float*)d_in[5];
    const float* ln1w = (const float*)d_in[6];
    const float* ln1b = (const float*)d_in[7];
    const float* ln2w = (const float*)d_in[8];
    const float* ln2b = (const float*)d_in[9];
    const float* W1   = (const float*)d_in[10];
    const float* b1   = (const float*)d_in[11];
    const float* W2   = (const float*)d_in[12];
    const float* b2   = (const float*)d_in[13];
    float* out = (float*)d_out;

    // Workspace (<=56 MB), att_x lives in d_out:
    //   [0,8)    h1 -> cc -> h2
    //   [8,16)   qb -> wo_bf[8,10) + w1_bf[10,18) -> w2_bf[8,16)
    //   [16,24)  kb
    //   [24,32)  vb ; [24,56) ff (after combine)
    //   [32,38)  wqkv_bf (dead before fattn)
    //   [32,48)  po (2 x 8 MiB attn O partials) ; [48,48.5) lz (2 x 256 KiB)
    char* wsb = (char*)d_ws;
    const size_t MB = 1024*1024;
    bf16*  h1      = (bf16*)(wsb + 0*MB);
    bf16*  qb      = (bf16*)(wsb + 8*MB);
    bf16*  kb      = (bf16*)(wsb + 16*MB);
    bf16*  vb      = (bf16*)(wsb + 24*MB);
    bf16*  wqkv_bf = (bf16*)(wsb + 32*MB);
    bf16*  po      = (bf16*)(wsb + 32*MB);
    float* lz      = (float*)(wsb + 48*MB);
    bf16*  cc      = (bf16*)(wsb + 0*MB);
    bf16*  wo_bf   = (bf16*)(wsb + 8*MB);
    bf16*  w1_bf   = (bf16*)(wsb + 10*MB);
    bf16*  h2      = (bf16*)(wsb + 0*MB);
    bf16*  ff      = (bf16*)(wsb + 24*MB);
    bf16*  w2_bf   = (bf16*)(wsb + 8*MB);

    QkvOut qa; qa.o[0] = qb; qa.o[1] = kb; qa.o[2] = vb;
    QkvOut qdummy = {};

    // 1. h1 = LN1(x)
    ln_kernel<float><<<NTOK, 256, 0, stream>>>(x, ln1w, ln1b, h1);

    // 2a. convert QKV weights -> wqkv_bf[3072][1024] bf16 N-major
    wcvt_qkv<<<dim3(2, 32, 48), 256, 0, stream>>>(Wq, Wk, Wv, wqkv_bf);

    // 2b. fused QKV as one 8-phase 256x256 GEMM (M=4096, N=3072, K=1024)
    gemm256_kernel<1><<<dim3(12, 16), 512, 0, stream>>>(
        h1, D_MODEL, wqkv_bf, D_MODEL, D_MODEL, nullptr, nullptr, 0, qa);

    // 3a. split-K flash attention -> O/l partials  (x=bh, y=raw tile, z=chunk)
    fattn_mfma<<<dim3(BATCH*N_HEADS, SEQ/128, 2), 256, 0, stream>>>(qb, kb, vb, po, lz);

    // 3b. combine partials -> concat
    attn_combine<<<NTOK, 256, 0, stream>>>(po, lz, cc);

    // 4a. convert Wo + W1 in one launch (qb/kb dead)
    wcvt_wo_w1<<<dim3(160, 32), 256, 0, stream>>>(Wo, W1, wo_bf, w1_bf);

    // 4b. att_x = x + cc @ Wo -> d_out (fp32): 3-deep counted-vmcnt pipeline
    mfma_gemm_pipe3<64,128,64,0,0,1,0><<<dim3(8,64), 256, 0, stream>>>(
        cc, D_MODEL, wo_bf, D_MODEL, nullptr, x, out, D_MODEL);

    // 5. h2 = LN2(att_x)
    ln_kernel<float><<<NTOK, 256, 0, stream>>>(out, ln2w, ln2b, h2);

    // 6. ff = GELU(h2 @ W1 + b1): 8-phase 256x256 GEMM (M=4096, N=4096, K=1024)
    gemm256_kernel<0><<<dim3(16, 16), 512, 0, stream>>>(
        h2, D_MODEL, w1_bf, D_MODEL, D_MODEL, b1, ff, D_FF, qdummy);

    // 7a. convert W2 (w1_bf/wo_bf dead)
    wcvt_kernel<<<dim3(D_MODEL/32, D_FF/32), 256, 0, stream>>>(W2, w2_bf, D_FF, D_MODEL);

    // 7b. out = att_x + ff @ W2 + b2: 3-deep counted-vmcnt pipeline
    mfma_gemm_pipe3<64,128,64,1,0,1,0><<<dim3(8,64), 256, 0, stream>>>(
        ff, D_FF, w2_bf, D_FF, b2, out, out, D_MODEL);
}

// Round 12
// 351.596 us; speedup vs baseline: 1.0555x; 1.0278x over previous
//
#include <hip/hip_runtime.h>
#include <hip/hip_bf16.h>
#include <math.h>

#define D_MODEL 1024
#define N_HEADS 16
#define D_HEAD  64
#define D_FF    4096
#define BATCH   2
#define SEQ     2048
#define NTOK    (BATCH*SEQ)

typedef __hip_bfloat16 bf16;
typedef __attribute__((ext_vector_type(8))) short short8;
typedef __attribute__((ext_vector_type(4))) float floatx4;

// ---------------- LayerNorm (wave-shuffle reduction) ----------------
template<typename TIN>
__global__ void ln_kernel(const TIN* __restrict__ x,
                          const float* __restrict__ w,
                          const float* __restrict__ b,
                          bf16* __restrict__ out) {
    int row = blockIdx.x;
    int tid = threadIdx.x;
    int wave = tid >> 6, lane = tid & 63;
    const long base = (long)row * D_MODEL;
    float v[4];
    float s = 0.f, sq = 0.f;
#pragma unroll
    for (int i = 0; i < 4; ++i) {
        float xv = (float)x[base + tid + i*256];
        v[i] = xv; s += xv; sq += xv*xv;
    }
#pragma unroll
    for (int m = 32; m >= 1; m >>= 1) {
        s  += __shfl_xor(s,  m, 64);
        sq += __shfl_xor(sq, m, 64);
    }
    __shared__ float r1[4], r2[4];
    if (lane == 0) { r1[wave] = s; r2[wave] = sq; }
    __syncthreads();
    float S  = r1[0] + r1[1] + r1[2] + r1[3];
    float SQ = r2[0] + r2[1] + r2[2] + r2[3];
    float mean = S * (1.f/D_MODEL);
    float var  = SQ * (1.f/D_MODEL) - mean*mean;
    float rstd = rsqrtf(var + 1e-5f);
#pragma unroll
    for (int i = 0; i < 4; ++i) {
        int c = tid + i*256;
        out[base + c] = __float2bfloat16((v[i] - mean) * rstd * w[c] + b[c]);
    }
}

// ---------------- weight convert+transpose: fp32 [K][N] -> bf16 [N][K] ----------------
__global__ __launch_bounds__(256) void wcvt_kernel(const float* __restrict__ W,
                                                   bf16* __restrict__ Wt,
                                                   int K, int N) {
    __shared__ float t[32][33];
    int n0 = blockIdx.x * 32, k0 = blockIdx.y * 32;
    int lx = threadIdx.x & 31, ly = threadIdx.x >> 5;
#pragma unroll
    for (int i = 0; i < 4; ++i) {
        int k = ly + i * 8;
        t[k][lx] = W[(long)(k0 + k) * N + n0 + lx];
    }
    __syncthreads();
#pragma unroll
    for (int i = 0; i < 4; ++i) {
        int n = ly + i * 8;
        Wt[(long)(n0 + n) * K + k0 + lx] = __float2bfloat16(t[lx][n]);
    }
}

// merged Wo+W1 convert (both K=1024): gx<32 -> Wo cols, else W1 cols
__global__ __launch_bounds__(256) void wcvt_wo_w1(const float* __restrict__ Wo,
                                                  const float* __restrict__ W1,
                                                  bf16* __restrict__ wo_bf,
                                                  bf16* __restrict__ w1_bf) {
    __shared__ float t[32][33];
    int gx = blockIdx.x;
    const float* W; bf16* Wt; int N, n0;
    if (gx < 32) { W = Wo; Wt = wo_bf; N = D_MODEL; n0 = gx * 32; }
    else         { W = W1; Wt = w1_bf; N = D_FF;    n0 = (gx - 32) * 32; }
    int k0 = blockIdx.y * 32;
    int lx = threadIdx.x & 31, ly = threadIdx.x >> 5;
#pragma unroll
    for (int i = 0; i < 4; ++i) {
        int k = ly + i * 8;
        t[k][lx] = W[(long)(k0 + k) * N + n0 + lx];
    }
    __syncthreads();
#pragma unroll
    for (int i = 0; i < 4; ++i) {
        int n = ly + i * 8;
        Wt[(long)(n0 + n) * D_MODEL + k0 + lx] = __float2bfloat16(t[lx][n]);
    }
}

// per-head QKV weight convert: -> wqkv_bf[3072][1024] bf16 N-major (n = mat*1024+head*64+d)
__global__ __launch_bounds__(256) void wcvt_qkv(const float* __restrict__ Wq,
                                                const float* __restrict__ Wk,
                                                const float* __restrict__ Wv,
                                                bf16* __restrict__ outp) {
    __shared__ float t[32][33];
    int z = blockIdx.z, mat = z >> 4, head = z & 15;
    const float* W = (mat == 0 ? Wq : mat == 1 ? Wk : Wv) + (long)head * D_MODEL * D_HEAD;
    bf16* Wt = outp + (long)z * D_HEAD * D_MODEL;
    int n0 = blockIdx.x * 32, k0 = blockIdx.y * 32;
    int lx = threadIdx.x & 31, ly = threadIdx.x >> 5;
#pragma unroll
    for (int i = 0; i < 4; ++i) {
        int k = ly + i * 8;
        t[k][lx] = W[(long)(k0 + k) * D_HEAD + n0 + lx];
    }
    __syncthreads();
#pragma unroll
    for (int i = 0; i < 4; ++i) {
        int n = ly + i * 8;
        Wt[(long)(n0 + n) * D_MODEL + k0 + lx] = __float2bfloat16(t[lx][n]);
    }
}

// ---------------- XCD-chunked block swizzle (requires nwg % 8 == 0) ----------------
__device__ inline void swz2d(int& bx, int& by) {
    int gx = gridDim.x;
    int nwg = gx * gridDim.y;
    int bid = blockIdx.y * gx + blockIdx.x;
    int swz = (bid & 7) * (nwg >> 3) + (bid >> 3);
    bx = swz % gx;
    by = swz / gx;
}

// ---------------- async stage: ROWS x 32 bf16 tile (64B rows, unpadded) ----------------
template<int ROWS>
__device__ inline void stage_tile(const bf16* g, int gstride, short* lds) {
    int lane = threadIdx.x & 63, wave = threadIdx.x >> 6;
#pragma unroll
    for (int it = 0; it < ROWS / 64; ++it) {
        int c = wave + it * 4;
        const bf16* gp = g + (long)(c * 16 + (lane >> 2)) * gstride + (lane & 3) * 8;
        short* lp = lds + c * 512 + lane * 8;
        __builtin_amdgcn_global_load_lds(
            (const __attribute__((address_space(1))) void*)gp,
            (__attribute__((address_space(3))) void*)lp, 16, 0, 0);
    }
}

// ---------------- sync / asm helpers ----------------
#define G256_BAR  asm volatile("s_barrier" ::: "memory")
#define G256_VM12 asm volatile("s_waitcnt vmcnt(12)" ::: "memory")
#define G256_VM6  asm volatile("s_waitcnt vmcnt(6)" ::: "memory")
#define G256_VM4  asm volatile("s_waitcnt vmcnt(4)" ::: "memory")
#define G256_VM0  asm volatile("s_waitcnt vmcnt(0)" ::: "memory")
#define G256_LGKM0 do { asm volatile("s_waitcnt lgkmcnt(0)" ::: "memory"); \
                        __builtin_amdgcn_sched_barrier(0); } while (0)

__device__ inline short8 rd128(unsigned ad) {
    short8 r;
    asm volatile("ds_read_b128 %0, %1" : "=v"(r) : "v"(ad));
    return r;
}

// ---------------- 3-deep counted-vmcnt pipeline GEMM (4b / 7b) ---------------------
template<int BM, int BN, int BK, int BIAS, int ACT, int RES, int OUTBF16>
__global__ __launch_bounds__(256) void mfma_gemm_pipe3(
    const bf16* __restrict__ A, int lda,
    const bf16* __restrict__ Wt, int K,
    const float* __restrict__ bias, const float* __restrict__ resid,
    void* __restrict__ Cout, int ldc)
{
    constexpr int MI  = BM / 32;
    constexpr int NR  = BN / 32;
    constexpr int ASZ = BM * BK;
    constexpr int BSZ = BN * BK;
    __shared__ short As[3 * BM * BK];
    __shared__ short Bs[3 * BN * BK];
    int bx, by; swz2d(bx, by);
    int row0 = by * BM, col0 = bx * BN;
    int tid = threadIdx.x, wave = tid >> 6, lane = tid & 63;
    int quad = lane >> 4, l16 = lane & 15;
    int wm = (wave >> 1) * (BM / 2);
    int wn = (wave & 1) * (BN / 2);
    const int NT = K / BK;

    auto stage = [&](int t, int buf) {
        int k0 = t * BK;
#pragma unroll
        for (int kk = 0; kk < BK; kk += 32) {
            stage_tile<BM>(A  + (long)row0 * lda + k0 + kk, lda,
                           As + buf * ASZ + (kk / 32) * BM * 32);
            stage_tile<BN>(Wt + (long)col0 * K   + k0 + kk, K,
                           Bs + buf * BSZ + (kk / 32) * BN * 32);
        }
    };

    unsigned asbase = (unsigned)(unsigned long long)(void*)&As[0];
    unsigned bsbase = (unsigned)(unsigned long long)(void*)&Bs[0];
    unsigned aRow[MI], bRow[NR];
#pragma unroll
    for (int mi = 0; mi < MI; ++mi)
        aRow[mi] = (unsigned)(((wm + mi * 16 + l16) * 32 + quad * 8) * 2);
#pragma unroll
    for (int ni = 0; ni < NR; ++ni)
        bRow[ni] = (unsigned)(((wn + ni * 16 + l16) * 32 + quad * 8) * 2);

    floatx4 acc[MI][NR];
#pragma unroll
    for (int mi = 0; mi < MI; ++mi)
#pragma unroll
        for (int ni = 0; ni < NR; ++ni)
            acc[mi][ni] = (floatx4){0.f, 0.f, 0.f, 0.f};

    stage(0, 0);
    if (NT > 1) stage(1, 1);
    if (NT > 2) stage(2, 2);

    int buf = 0;
    for (int i = 0; i < NT; ++i) {
        if (i + 2 < NT)      { G256_VM12; }
        else if (i + 1 < NT) { G256_VM6;  }
        else                 { G256_VM0;  }
        G256_BAR;

        short8 af[BK / 32][MI], bfr[BK / 32][NR];
#pragma unroll
        for (int p = 0; p < BK / 32; ++p) {
            unsigned ab = asbase + (unsigned)((buf * ASZ + p * BM * 32) * 2);
            unsigned bb = bsbase + (unsigned)((buf * BSZ + p * BN * 32) * 2);
#pragma unroll
            for (int mi = 0; mi < MI; ++mi) af[p][mi] = rd128(ab + aRow[mi]);
#pragma unroll
            for (int ni = 0; ni < NR; ++ni) bfr[p][ni] = rd128(bb + bRow[ni]);
        }
        G256_LGKM0;
#pragma unroll
        for (int p = 0; p < BK / 32; ++p)
#pragma unroll
            for (int mi = 0; mi < MI; ++mi)
#pragma unroll
                for (int ni = 0; ni < NR; ++ni)
                    acc[mi][ni] = __builtin_amdgcn_mfma_f32_16x16x32_bf16(
                        af[p][mi], bfr[p][ni], acc[mi][ni], 0, 0, 0);

        G256_BAR;
        if (i + 3 < NT) stage(i + 3, buf);
        buf = (buf == 2) ? 0 : buf + 1;
    }

#pragma unroll
    for (int mi = 0; mi < MI; ++mi) {
#pragma unroll
        for (int ni = 0; ni < NR; ++ni) {
#pragma unroll
            for (int r = 0; r < 4; ++r) {
                int row = row0 + wm + mi * 16 + quad * 4 + r;
                int col = col0 + wn + ni * 16 + l16;
                float v = acc[mi][ni][r];
                if (BIAS) v += bias[col];
                if (ACT == 1) {
                    float x2 = v * v;
                    float arg = fminf(v * fmaf(0.1029392f, x2, 2.3021182f), 20.f);
                    float t = exp2f(arg);
                    v = v * t * __builtin_amdgcn_rcpf(t + 1.f);
                }
                long idx = (long)row * ldc + col;
                if (RES == 1) v += resid[idx];
                if (OUTBF16) ((bf16*)Cout)[idx] = __float2bfloat16(v);
                else         ((float*)Cout)[idx] = v;
            }
        }
    }
}

// ================= 8-phase 256x256 GEMM (QKV / FFN1) ===============================
struct QkvOut { bf16* o[3]; };

#define RG(buf,mat,kh) (((buf)*4 + (mat)*2 + (kh)) * 8192)

__device__ inline void stage2(const bf16* g0, const bf16* g1, int koff, short* lp) {
    __builtin_amdgcn_global_load_lds(
        (const __attribute__((address_space(1))) void*)(g0 + koff),
        (__attribute__((address_space(3))) void*)lp, 16, 0, 0);
    __builtin_amdgcn_global_load_lds(
        (const __attribute__((address_space(1))) void*)(g1 + koff),
        (__attribute__((address_space(3))) void*)(lp + 4096), 16, 0, 0);
}

template<int MH>
__device__ inline void rd_frags_asm(unsigned ldsbase, int ra, int rb,
                                    const unsigned (&aoff)[8], const unsigned (&boff)[4],
                                    short8 (&areg)[4], short8 (&breg)[4]) {
    if (MH == 0) {
#pragma unroll
        for (int ni = 0; ni < 4; ++ni) {
            unsigned ad = ldsbase + (unsigned)(rb * 2) + boff[ni];
            asm volatile("ds_read_b128 %0, %1" : "=v"(breg[ni]) : "v"(ad));
        }
    }
#pragma unroll
    for (int mi = 0; mi < 4; ++mi) {
        unsigned ad = ldsbase + (unsigned)(ra * 2) + aoff[MH * 4 + mi];
        asm volatile("ds_read_b128 %0, %1" : "=v"(areg[mi]) : "v"(ad));
    }
}

template<int MH>
__device__ inline void do_mfma16(const short8 (&areg)[4], const short8 (&breg)[4],
                                 floatx4 (&acc)[8][4]) {
    __builtin_amdgcn_s_setprio(1);
#pragma unroll
    for (int mi = 0; mi < 4; ++mi)
#pragma unroll
        for (int ni = 0; ni < 4; ++ni)
            acc[MH * 4 + mi][ni] = __builtin_amdgcn_mfma_f32_16x16x32_bf16(
                areg[mi], breg[ni], acc[MH * 4 + mi][ni], 0, 0, 0);
    __builtin_amdgcn_s_setprio(0);
}

// EPI: 0 = bias+GELU -> bf16 (FFN1)   1 = QKV scatter
template<int EPI>
__global__ __launch_bounds__(512, 1) void gemm256_kernel(
    const bf16* __restrict__ A, int lda,
    const bf16* __restrict__ Wt, int ldw, int K,
    const float* __restrict__ bias,
    bf16* __restrict__ Cout, int ldc, QkvOut qa)
{
    __shared__ short lds[65536];   // 128 KiB
    const int NT = K / 64;
    int bx, by; swz2d(bx, by);
    int row0 = by * 256, col0 = bx * 256;
    int tid = threadIdx.x;
    int lane = tid & 63, wave = tid >> 6;
    int quad = lane >> 4, l16 = lane & 15;
    int wr = wave >> 2, wc = wave & 3;

    int srow = tid >> 2, slot = tid & 3;
    int cA0 = slot ^ ((srow >> 1) & 3);
    int cA1 = slot ^ (((srow + 128) >> 1) & 3);
    const bf16* a0 = A  + (long)(row0 + srow) * lda + cA0 * 8;
    const bf16* a1 = A  + (long)(row0 + srow + 128) * lda + cA1 * 8;
    const bf16* b0 = Wt + (long)(col0 + srow) * ldw + cA0 * 8;
    const bf16* b1 = Wt + (long)(col0 + srow + 128) * ldw + cA1 * 8;
    short* lt = lds + tid * 8;

    unsigned ldsbase = (unsigned)(unsigned long long)(void*)&lds[0];
    unsigned aoff[8], boff[4];
#pragma unroll
    for (int mi = 0; mi < 8; ++mi) {
        int row = wr * 128 + mi * 16 + l16;
        int sl = quad ^ ((row >> 1) & 3);
        aoff[mi] = (unsigned)((row * 32 + sl * 8) * 2);
    }
#pragma unroll
    for (int ni = 0; ni < 4; ++ni) {
        int row = wc * 64 + ni * 16 + l16;
        int sl = quad ^ ((row >> 1) & 3);
        boff[ni] = (unsigned)((row * 32 + sl * 8) * 2);
    }

    floatx4 acc[8][4];
#pragma unroll
    for (int mi = 0; mi < 8; ++mi)
#pragma unroll
        for (int ni = 0; ni < 4; ++ni)
            acc[mi][ni] = (floatx4){0.f, 0.f, 0.f, 0.f};

    stage2(a0, a1, 0,  lt + RG(0,0,0));
    stage2(b0, b1, 0,  lt + RG(0,1,0));
    stage2(a0, a1, 32, lt + RG(0,0,1));
    stage2(b0, b1, 32, lt + RG(0,1,1));
    stage2(a0, a1, 64, lt + RG(1,0,0));
    stage2(b0, b1, 64, lt + RG(1,1,0));
    G256_VM4;
    G256_BAR;

    short8 areg[4], breg[4];

    for (int i = 0; i < NT / 2; ++i) {
        int T = 2 * i;
        bool s2 = (T + 2 < NT);
        bool s3 = (T + 3 < NT);
        int k1off = (T + 1) * 64;
        int k2off = (T + 2) * 64;
        int k3off = (T + 3) * 64;

        rd_frags_asm<0>(ldsbase, RG(0,0,0), RG(0,1,0), aoff, boff, areg, breg);
        stage2(a0, a1, k1off + 32, lt + RG(1,0,1));
        G256_BAR;
        G256_LGKM0;
        do_mfma16<0>(areg, breg, acc);
        G256_BAR;

        rd_frags_asm<1>(ldsbase, RG(0,0,0), RG(0,1,0), aoff, boff, areg, breg);
        stage2(b0, b1, k1off + 32, lt + RG(1,1,1));
        G256_BAR;
        G256_LGKM0;
        do_mfma16<1>(areg, breg, acc);
        G256_BAR;

        rd_frags_asm<0>(ldsbase, RG(0,0,1), RG(0,1,1), aoff, boff, areg, breg);
        if (s2) stage2(a0, a1, k2off, lt + RG(0,0,0));
        G256_BAR;
        G256_LGKM0;
        do_mfma16<0>(areg, breg, acc);
        G256_BAR;

        rd_frags_asm<1>(ldsbase, RG(0,0,1), RG(0,1,1), aoff, boff, areg, breg);
        if (s2) stage2(b0, b1, k2off, lt + RG(0,1,0));
        G256_BAR;
        G256_LGKM0;
        do_mfma16<1>(areg, breg, acc);
        if (s2) { G256_VM4; } else { G256_VM0; }
        G256_BAR;

        rd_frags_asm<0>(ldsbase, RG(1,0,0), RG(1,1,0), aoff, boff, areg, breg);
        if (s2) stage2(a0, a1, k2off + 32, lt + RG(0,0,1));
        G256_BAR;
        G256_LGKM0;
        do_mfma16<0>(areg, breg, acc);
        G256_BAR;

        rd_frags_asm<1>(ldsbase, RG(1,0,0), RG(1,1,0), aoff, boff, areg, breg);
        if (s2) stage2(b0, b1, k2off + 32, lt + RG(0,1,1));
        G256_BAR;
        G256_LGKM0;
        do_mfma16<1>(areg, breg, acc);
        G256_BAR;

        rd_frags_asm<0>(ldsbase, RG(1,0,1), RG(1,1,1), aoff, boff, areg, breg);
        if (s3) stage2(a0, a1, k3off, lt + RG(1,0,0));
        G256_BAR;
        G256_LGKM0;
        do_mfma16<0>(areg, breg, acc);
        G256_BAR;

        rd_frags_asm<1>(ldsbase, RG(1,0,1), RG(1,1,1), aoff, boff, areg, breg);
        if (s3) stage2(b0, b1, k3off, lt + RG(1,1,0));
        G256_BAR;
        G256_LGKM0;
        do_mfma16<1>(areg, breg, acc);
        if (s3) { G256_VM4; } else { G256_VM0; }
        G256_BAR;
    }

#pragma unroll
    for (int mi = 0; mi < 8; ++mi) {
#pragma unroll
        for (int ni = 0; ni < 4; ++ni) {
#pragma unroll
            for (int r = 0; r < 4; ++r) {
                int row = row0 + wr * 128 + mi * 16 + quad * 4 + r;
                int col = col0 + wc * 64 + ni * 16 + l16;
                float v = acc[mi][ni][r];
                if constexpr (EPI == 0) {
                    v += bias[col];
                    float x2 = v * v;
                    float arg = fminf(v * fmaf(0.1029392f, x2, 2.3021182f), 20.f);
                    float t = exp2f(arg);
                    v = v * t * __builtin_amdgcn_rcpf(t + 1.f);
                    Cout[(long)row * ldc + col] = __float2bfloat16(v);
                } else {
                    int mat = col >> 10, hd = (col >> 6) & 15, d = col & 63;
                    int b = row >> 11, s = row & 2047;
                    qa.o[mat][(((long)(b * 16 + hd) * SEQ + s) << 6) + d] =
                        __float2bfloat16(v);
                }
            }
        }
    }
}

// ---------------- MFMA flash attention v8: balanced multi-chunk split-K -----------
// Inner loop identical to v6 (T14 + T5). Work partition changed so EVERY block does
// <= 8 kt-visits: tiles 0-7 split 2-way (as before), tiles 8-15 split 4-way. Extra
// partials po2/po3 cover only rows 1024-2047. Big tiles dispatch first (y reversed);
// 1536 blocks > 1024 residency -> short blocks backfill the tail.
__global__ __launch_bounds__(256) void fattn_mfma(const bf16* __restrict__ q,
                                                  const bf16* __restrict__ k,
                                                  const bf16* __restrict__ v,
                                                  bf16* __restrict__ po,
                                                  bf16* __restrict__ po23,
                                                  float* __restrict__ lz) {
    int yy = 47 - (int)blockIdx.y;               // big tiles first
    int tile, ch, NC;
    if (yy < 16) { tile = yy >> 1; ch = yy & 1; NC = 2; }
    else { int z = yy - 16; tile = 8 + (z >> 2); ch = z & 3; NC = 4; }
    int bh = blockIdx.x;
    int tid = threadIdx.x;
    int wave = tid >> 6, lane = tid & 63;
    int quad = lane >> 4, l16 = lane & 15;
    const long base = (long)bh * SEQ * D_HEAD;
    const int r0g = tile * 128;
    const int Vt = 2 * tile + 2;
    const int kt0 = (ch * Vt) / NC;
    const int kt1 = ((ch + 1) * Vt) / NC - 1;

    bf16* pob; float* lzb; int rbase;
    if (ch < 2) {
        pob = po + (long)ch * 32 * SEQ * 64 + (long)bh * SEQ * 64;
        lzb = lz + (long)ch * 32 * SEQ + (long)bh * SEQ;
        rbase = 0;
    } else {
        pob = po23 + (long)(ch - 2) * 32 * 1024 * 64 + (long)bh * 1024 * 64;
        lzb = lz + 64 * SEQ + (long)(ch - 2) * 32 * 1024 + (long)bh * 1024;
        rbase = 1024;
    }

    __shared__ short Ks[64 * 72];
    __shared__ short Vt_[64 * 72];
    __shared__ short Ps[4][32 * 72];

    short8 qf[2][2];
#pragma unroll
    for (int rb = 0; rb < 2; ++rb) {
        const short* qrow = (const short*)(q + base +
            (long)(r0g + wave * 32 + rb * 16 + l16) * D_HEAD);
        qf[rb][0] = *(const short8*)(qrow + quad * 8);
        qf[rb][1] = *(const short8*)(qrow + 32 + quad * 8);
#pragma unroll
        for (int c = 0; c < 2; ++c)
#pragma unroll
            for (int j = 0; j < 8; ++j) {
                float f = __uint_as_float(((unsigned)(unsigned short)qf[rb][c][j]) << 16)
                          * 0.18033688f;
                qf[rb][c][j] = __builtin_bit_cast(short, __float2bfloat16(f));
            }
    }

    short8 onesf;
    {
        short o1 = (l16 == 0) ? (short)0x3F80 : (short)0;
#pragma unroll
        for (int j = 0; j < 8; ++j) onesf[j] = o1;
    }

    floatx4 o[2][4];
#pragma unroll
    for (int rb = 0; rb < 2; ++rb)
#pragma unroll
        for (int nb = 0; nb < 4; ++nb) o[rb][nb] = (floatx4){0.f, 0.f, 0.f, 0.f};
    floatx4 l4[2] = {(floatx4){0.f,0.f,0.f,0.f}, (floatx4){0.f,0.f,0.f,0.f}};

    // staged K/V registers (async-STAGE split, T14)
    uint4 kr0, kr1, va4, vb4;
    auto ldKV = [&](int kt) {
        const short* krow = (const short*)(k + base +
            (long)(kt * 64 + (tid >> 2)) * D_HEAD);
        int c = tid & 3;
        kr0 = *(const uint4*)(krow + c * 16);
        kr1 = *(const uint4*)(krow + c * 16 + 8);
        int tp = (tid & 31) * 2;
        int d0 = ((tid >> 5) & 7) * 8;
        const short* v0 = (const short*)(v + base + (long)(kt * 64 + tp) * D_HEAD + d0);
        va4 = *(const uint4*)v0;
        vb4 = *(const uint4*)(v0 + D_HEAD);
    };

    ldKV(kt0);

    for (int kt = kt0; kt <= kt1; ++kt) {
        __syncthreads();     // previous compute done; Ks/Vt free
        {
            int t = tid >> 2, c = tid & 3;
            *(uint4*)&Ks[t * 72 + c * 16]     = kr0;
            *(uint4*)&Ks[t * 72 + c * 16 + 8] = kr1;
        }
        {
            int tp = (tid & 31) * 2;
            int d0 = ((tid >> 5) & 7) * 8;
            short va[8], vb[8];
            *(uint4*)va = va4;
            *(uint4*)vb = vb4;
#pragma unroll
            for (int j = 0; j < 8; ++j) {
                unsigned pk = (unsigned)(unsigned short)va[j] |
                              ((unsigned)(unsigned short)vb[j] << 16);
                *(unsigned*)&Vt_[(d0 + j) * 72 + tp] = pk;
            }
        }
        if (kt < kt1) ldKV(kt + 1);   // next tile's loads hide under compute
        __syncthreads();

        if (kt * 64 > r0g + wave * 32 + 31) continue;

        floatx4 s[2][4];
        __builtin_amdgcn_s_setprio(1);
#pragma unroll
        for (int nb = 0; nb < 4; ++nb) {
            short8 kf0 = *(const short8*)&Ks[(nb * 16 + l16) * 72 + quad * 8];
            short8 kf1 = *(const short8*)&Ks[(nb * 16 + l16) * 72 + 32 + quad * 8];
#pragma unroll
            for (int rb = 0; rb < 2; ++rb) {
                floatx4 z4 = (floatx4){0.f, 0.f, 0.f, 0.f};
                z4 = __builtin_amdgcn_mfma_f32_16x16x32_bf16(qf[rb][0], kf0, z4, 0, 0, 0);
                z4 = __builtin_amdgcn_mfma_f32_16x16x32_bf16(qf[rb][1], kf1, z4, 0, 0, 0);
                s[rb][nb] = z4;
            }
        }
        __builtin_amdgcn_s_setprio(0);

        if (kt >= 2 * tile) {
#pragma unroll
            for (int rb = 0; rb < 2; ++rb) {
                int qg = r0g + wave * 32 + rb * 16 + quad * 4;
#pragma unroll
                for (int nb = 0; nb < 4; ++nb) {
                    int kg = kt * 64 + nb * 16 + l16;
#pragma unroll
                    for (int r = 0; r < 4; ++r)
                        if (kg > qg + r) s[rb][nb][r] = -1e30f;
                }
            }
        }

        short* Pw = &Ps[wave][0];
#pragma unroll
        for (int rb = 0; rb < 2; ++rb)
#pragma unroll
            for (int nb = 0; nb < 4; ++nb)
#pragma unroll
                for (int r = 0; r < 4; ++r) {
                    float p = exp2f(s[rb][nb][r]);
                    Pw[(rb * 16 + quad * 4 + r) * 72 + nb * 16 + l16] =
                        __builtin_bit_cast(short, __float2bfloat16(p));
                }

        short8 pf[2][2];
#pragma unroll
        for (int rb = 0; rb < 2; ++rb) {
            pf[rb][0] = *(const short8*)&Pw[(rb * 16 + l16) * 72 + quad * 8];
            pf[rb][1] = *(const short8*)&Pw[(rb * 16 + l16) * 72 + 32 + quad * 8];
        }
        __builtin_amdgcn_s_setprio(1);
#pragma unroll
        for (int nb = 0; nb < 4; ++nb) {
            short8 vf0 = *(const short8*)&Vt_[(nb * 16 + l16) * 72 + quad * 8];
            short8 vf1 = *(const short8*)&Vt_[(nb * 16 + l16) * 72 + 32 + quad * 8];
#pragma unroll
            for (int rb = 0; rb < 2; ++rb) {
                o[rb][nb] = __builtin_amdgcn_mfma_f32_16x16x32_bf16(pf[rb][0], vf0, o[rb][nb], 0, 0, 0);
                o[rb][nb] = __builtin_amdgcn_mfma_f32_16x16x32_bf16(pf[rb][1], vf1, o[rb][nb], 0, 0, 0);
            }
        }
#pragma unroll
        for (int rb = 0; rb < 2; ++rb) {
            l4[rb] = __builtin_amdgcn_mfma_f32_16x16x32_bf16(pf[rb][0], onesf, l4[rb], 0, 0, 0);
            l4[rb] = __builtin_amdgcn_mfma_f32_16x16x32_bf16(pf[rb][1], onesf, l4[rb], 0, 0, 0);
        }
        __builtin_amdgcn_s_setprio(0);
    }

    // epilogue: unnormalized O partial (bf16) + l partial (fp32)
#pragma unroll
    for (int rb = 0; rb < 2; ++rb) {
#pragma unroll
        for (int nb = 0; nb < 4; ++nb)
#pragma unroll
            for (int r = 0; r < 4; ++r) {
                int row = r0g + wave * 32 + rb * 16 + quad * 4 + r;
                pob[(long)(row - rbase) * 64 + nb * 16 + l16] =
                    __float2bfloat16(o[rb][nb][r]);
            }
        if (l16 == 0) {
#pragma unroll
            for (int r = 0; r < 4; ++r) {
                int row = r0g + wave * 32 + rb * 16 + quad * 4 + r;
                lzb[row - rbase] = l4[rb][r];
            }
        }
    }
}

// combine: 2 partials (rows<1024) or 4 (rows>=1024); one block per token row
__global__ __launch_bounds__(256) void attn_combine(const bf16* __restrict__ po,
                                                    const bf16* __restrict__ po23,
                                                    const float* __restrict__ lz,
                                                    bf16* __restrict__ cc) {
    const long CH = 32L * SEQ * 64;
    const long CH23 = 32L * 1024 * 64;
    int row = blockIdx.x;
    int b = row >> 11, s = row & 2047;
    int tid = threadIdx.x;
    int col = tid * 4;
    int h = col >> 6, d = col & 63;
    long pidx = ((long)(b * 16 + h) * SEQ + s) * 64 + d;
    uint2 u0 = *(const uint2*)((const unsigned short*)po + pidx);
    uint2 u1 = *(const uint2*)((const unsigned short*)po + CH + pidx);
    long li = (long)(b * 16 + h) * SEQ + s;
    float lsum = lz[li] + lz[32L * SEQ + li];
    unsigned ua[4] = {u0.x & 0xFFFFu, u0.x >> 16, u0.y & 0xFFFFu, u0.y >> 16};
    unsigned ub[4] = {u1.x & 0xFFFFu, u1.x >> 16, u1.y & 0xFFFFu, u1.y >> 16};
    float acc[4];
#pragma unroll
    for (int i = 0; i < 4; ++i)
        acc[i] = __uint_as_float(ua[i] << 16) + __uint_as_float(ub[i] << 16);
    if (s >= 1024) {
        long p2 = ((long)(b * 16 + h) * 1024 + (s - 1024)) * 64 + d;
        uint2 u2 = *(const uint2*)((const unsigned short*)po23 + p2);
        uint2 u3 = *(const uint2*)((const unsigned short*)po23 + CH23 + p2);
        long l2 = (long)(b * 16 + h) * 1024 + (s - 1024);
        lsum += lz[64L * SEQ + l2] + lz[64L * SEQ + 32L * 1024 + l2];
        unsigned uc[4] = {u2.x & 0xFFFFu, u2.x >> 16, u2.y & 0xFFFFu, u2.y >> 16};
        unsigned ud[4] = {u3.x & 0xFFFFu, u3.x >> 16, u3.y & 0xFFFFu, u3.y >> 16};
#pragma unroll
        for (int i = 0; i < 4; ++i)
            acc[i] += __uint_as_float(uc[i] << 16) + __uint_as_float(ud[i] << 16);
    }
    float linv = 1.f / lsum;
    unsigned short rr[4];
#pragma unroll
    for (int i = 0; i < 4; ++i)
        rr[i] = __builtin_bit_cast(unsigned short, __float2bfloat16(acc[i] * linv));
    uint2 w;
    w.x = (unsigned)rr[0] | ((unsigned)rr[1] << 16);
    w.y = (unsigned)rr[2] | ((unsigned)rr[3] << 16);
    *(uint2*)((unsigned short*)cc + (long)row * D_MODEL + col) = w;
}

extern "C" void kernel_launch(void* const* d_in, const int* in_sizes, int n_in,
                              void* d_out, int out_size, void* d_ws, size_t ws_size,
                              hipStream_t stream) {
    const float* x    = (const float*)d_in[0];
    const float* Wq   = (const float*)d_in[2];
    const float* Wk   = (const float*)d_in[3];
    const float* Wv   = (const float*)d_in[4];
    const float* Wo   = (const float*)d_in[5];
    const float* ln1w = (const float*)d_in[6];
    const float* ln1b = (const float*)d_in[7];
    const float* ln2w = (const float*)d_in[8];
    const float* ln2b = (const float*)d_in[9];
    const float* W1   = (const float*)d_in[10];
    const float* b1   = (const float*)d_in[11];
    const float* W2   = (const float*)d_in[12];
    const float* b2   = (const float*)d_in[13];
    float* out = (float*)d_out;

    // Workspace (<=56 MB), att_x lives in d_out. Timeline:
    //   phase A (LN1/QKV):     h1 [0,8), qb [8,16), kb [16,24), vb [24,32), wqkv [32,38)
    //   phase B (fattn):       po23 [0,8) (rows 1024+ partials), po [32,48), lz [48,48.75)
    //   phase C (combine):     cc [8,16) (qb dead)
    //   phase D (Wo/W1 cvt):   wo_bf [0,2), w1_bf [16,24) (kb dead)
    //   phase E (4b,LN2,FFN1): h2 [8,16) (cc dead after 4b), ff [24,56) (vb/po/lz dead)
    //   phase F (W2 cvt, 7b):  w2_bf [0,8) (po23/wo dead)
    char* wsb = (char*)d_ws;
    const size_t MB = 1024*1024;
    bf16*  h1      = (bf16*)(wsb + 0*MB);
    bf16*  qb      = (bf16*)(wsb + 8*MB);
    bf16*  kb      = (bf16*)(wsb + 16*MB);
    bf16*  vb      = (bf16*)(wsb + 24*MB);
    bf16*  wqkv_bf = (bf16*)(wsb + 32*MB);
    bf16*  po      = (bf16*)(wsb + 32*MB);
    bf16*  po23    = (bf16*)(wsb + 0*MB);
    float* lz      = (float*)(wsb + 48*MB);
    bf16*  cc      = (bf16*)(wsb + 8*MB);
    bf16*  wo_bf   = (bf16*)(wsb + 0*MB);
    bf16*  w1_bf   = (bf16*)(wsb + 16*MB);
    bf16*  h2      = (bf16*)(wsb + 8*MB);
    bf16*  ff      = (bf16*)(wsb + 24*MB);
    bf16*  w2_bf   = (bf16*)(wsb + 0*MB);

    QkvOut qa; qa.o[0] = qb; qa.o[1] = kb; qa.o[2] = vb;
    QkvOut qdummy = {};

    // 1. h1 = LN1(x)
    ln_kernel<float><<<NTOK, 256, 0, stream>>>(x, ln1w, ln1b, h1);

    // 2a. convert QKV weights -> wqkv_bf[3072][1024] bf16 N-major
    wcvt_qkv<<<dim3(2, 32, 48), 256, 0, stream>>>(Wq, Wk, Wv, wqkv_bf);

    // 2b. fused QKV as one 8-phase 256x256 GEMM (M=4096, N=3072, K=1024)
    gemm256_kernel<1><<<dim3(12, 16), 512, 0, stream>>>(
        h1, D_MODEL, wqkv_bf, D_MODEL, D_MODEL, nullptr, nullptr, 0, qa);

    // 3a. balanced split-K flash attention (every block <= 8 kt-visits)
    fattn_mfma<<<dim3(BATCH*N_HEADS, 48), 256, 0, stream>>>(qb, kb, vb, po, po23, lz);

    // 3b. combine partials -> concat
    attn_combine<<<NTOK, 256, 0, stream>>>(po, po23, lz, cc);

    // 4a. convert Wo + W1 in one launch (qb/kb dead)
    wcvt_wo_w1<<<dim3(160, 32), 256, 0, stream>>>(Wo, W1, wo_bf, w1_bf);

    // 4b. att_x = x + cc @ Wo -> d_out (fp32): 3-deep counted-vmcnt pipeline
    mfma_gemm_pipe3<64,128,64,0,0,1,0><<<dim3(8,64), 256, 0, stream>>>(
        cc, D_MODEL, wo_bf, D_MODEL, nullptr, x, out, D_MODEL);

    // 5. h2 = LN2(att_x)
    ln_kernel<float><<<NTOK, 256, 0, stream>>>(out, ln2w, ln2b, h2);

    // 6. ff = GELU(h2 @ W1 + b1): 8-phase 256x256 GEMM (M=4096, N=4096, K=1024)
    gemm256_kernel<0><<<dim3(16, 16), 512, 0, stream>>>(
        h2, D_MODEL, w1_bf, D_MODEL, D_MODEL, b1, ff, D_FF, qdummy);

    // 7a. convert W2 (wo_bf/po23 dead)
    wcvt_kernel<<<dim3(D_MODEL/32, D_FF/32), 256, 0, stream>>>(W2, w2_bf, D_FF, D_MODEL);

    // 7b. out = att_x + ff @ W2 + b2: 3-deep counted-vmcnt pipeline
    mfma_gemm_pipe3<64,128,64,1,0,1,0><<<dim3(8,64), 256, 0, stream>>>(
        ff, D_FF, w2_bf, D_FF, b2, out, out, D_MODEL);
}